// Round 2
// baseline (3463.814 us; speedup 1.0000x reference)
//
#include <hip/hip_runtime.h>
#include <cstdint>
#include <cstddef>

// ---------------------------------------------------------------------------
// Model_xLSTM: B=128 S=256 NF=32 E=4 D=256 H=4 DI=512 DHM=128 DHS=64 K=4 FF=352
// Round 1: correctness-first, slimmed workspace (254 MiB), fused flash-style
// mLSTM attention (no S x S materialization), host-side sanity guard.
// Runtime input-dtype detection (fp32 vs bf16) via m_ln_g (all ones).
// ---------------------------------------------------------------------------

using u16 = unsigned short;
using u32 = unsigned int;

#define DEVINL __device__ __forceinline__

DEVINL float b2f(u16 u){ u32 x = ((u32)u) << 16; return __builtin_bit_cast(float, x); }
DEVINL u16 f2b(float f){
  u32 x = __builtin_bit_cast(u32, f);
  u32 r = x + 0x7FFFu + ((x >> 16) & 1u);   // RTNE
  return (u16)(r >> 16);
}
DEVINL float ldval(float x){ return x; }
DEVINL float ldval(u16 x){ return b2f(x); }
DEVINL void stval(float* p, float v){ *p = v; }
DEVINL void stval(u16* p, float v){ *p = f2b(v); }

// ----------------------------- input table ---------------------------------
constexpr int IN_N = 56;
constexpr long long IN_SIZES[IN_N] = {
  1048576, 128, 128, 404, 28, 10240, 256, 256, 256,
  262144, 1024, 2048, 512,
  262144, 512, 262144, 512, 262144, 512,
  6144, 4, 6144, 4,
  512, 512, 512, 131072, 256,
  256, 256, 1024, 256,
  65536, 256, 65536, 256, 65536, 256, 65536, 256,
  16384, 16384, 16384, 16384,
  256, 256,
  256, 256, 180224, 704, 90112, 256,
  16384, 64, 192, 3 };

struct CvOff { long long off[IN_N+1]; };
constexpr CvOff make_off(){
  CvOff o{};
  long long a = 0;
  for (int i = 0; i < IN_N; i++){
    o.off[i] = a;
    long long s = IN_SIZES[i];
    if (i == 1 || i == 2) s = 0;           // int inputs: not converted
    a += s;
  }
  o.off[IN_N] = a;
  return o;
}
constexpr CvOff CVOFF = make_off();
constexpr long long CV_TOTAL = CVOFF.off[IN_N];

// ----------------------------- ws layout (float units) ---------------------
constexpr long long alignup(long long x){ return ((x + 255) / 256) * 256; }
constexpr long long TOK = 32768;            // B*S
constexpr long long OFF_FLAG = alignup(CV_TOTAL);
constexpr long long OFF_IP  = OFF_FLAG + 64;
constexpr long long OFF_FP  = OFF_IP  + 131072;
constexpr long long OFF_F   = OFF_FP  + 131072;
constexpr long long OFF_G   = OFF_F   + 131072;
constexpr long long OFF_M   = OFF_G   + 131072;
constexpr long long OFF_X   = OFF_M   + 131072;           // T x 256 fp32
constexpr long long OFF_XN  = OFF_X   + TOK*256;          // T x 256 bf16
constexpr long long OFF_UP  = OFF_XN  + TOK*128;          // T x 1024 bf16 (xm|zg)
constexpr long long OFF_A   = OFF_UP  + TOK*512;          // T x 512 bf16 (a / AC / P)
constexpr long long OFF_Q   = OFF_A   + TOK*256;          // T x 512 bf16 (q / Y / ZT fp32)
constexpr long long OFF_K   = OFF_Q   + TOK*256;          // T x 512 bf16 (k / IT fp32)
constexpr long long OFF_V   = OFF_K   + TOK*256;          // T x 512 bf16 (CAT / v / FT fp32)
constexpr long long WS_END  = OFF_V   + TOK*256;          // ~66.45M floats = 254 MiB

// ----------------------------- kernels -------------------------------------

__global__ void detect_kernel(const void* mlng, int* flag){
  if (threadIdx.x == 0){
    u32 u = *(const u32*)mlng;
    *flag = (u == 0x3F803F80u) ? 1 : 0;
  }
}

struct InPtrs { const void* p[IN_N]; };

__global__ __launch_bounds__(256) void convert_kernel(InPtrs ptrs, float* __restrict__ cv,
                                                      const int* __restrict__ flag){
  long long gid = (long long)blockIdx.x * 256 + threadIdx.x;
  if (gid >= CV_TOTAL) return;
  int seg = 0;
#pragma unroll
  for (int i = 1; i < IN_N; i++) seg += (gid >= CVOFF.off[i]) ? 1 : 0;
  long long local = gid - CVOFF.off[seg];
  float v;
  if (*flag) v = b2f(((const u16*)ptrs.p[seg])[local]);
  else       v = ((const float*)ptrs.p[seg])[local];
  cv[gid] = v;
}

__global__ __launch_bounds__(256) void cat_kernel(const float* __restrict__ xs,
    const int* __restrict__ xe, const int* __restrict__ xp,
    const float* __restrict__ ee, const float* __restrict__ ep,
    float* __restrict__ CAT){
  int gid = blockIdx.x * 256 + threadIdx.x;   // T*40
  int c = gid % 40; int t = gid / 40; int b = t >> 8;
  float v;
  if (c < 32)      v = xs[(size_t)t*32 + c];
  else if (c < 36) v = ee[xe[b]*4 + (c - 32)];
  else             v = ep[xp[b]*4 + (c - 36)];
  CAT[(size_t)t*40 + c] = v;
}

// generic tiled GEMM: C[M,N] = A[M,K] @ W[K,N] + bias (+resid)
template<typename TA, typename TC>
__global__ __launch_bounds__(256) void gemm_kernel(
    const TA* __restrict__ A, int lda,
    const float* __restrict__ Wm, const float* __restrict__ bias,
    TC* __restrict__ Cc, int ldc, const float* __restrict__ resid,
    int M, int N, int K)
{
  __shared__ float As[16][68];
  __shared__ float Bs[16][68];
  const int bm = blockIdx.y * 64, bn = blockIdx.x * 64;
  const int tid = threadIdx.x, tx = tid & 15, ty = tid >> 4;
  float acc[4][4] = {};
  for (int k0 = 0; k0 < K; k0 += 16){
#pragma unroll
    for (int i = 0; i < 4; i++){
      int idx = tid + i*256;
      int m = idx >> 4, kq = idx & 15;
      As[kq][m] = (k0 + kq < K) ? ldval(A[(size_t)(bm + m)*lda + k0 + kq]) : 0.f;
      int kk = idx >> 6, n = idx & 63;
      Bs[kk][n] = (k0 + kk < K) ? Wm[(size_t)(k0 + kk)*N + bn + n] : 0.f;
    }
    __syncthreads();
#pragma unroll
    for (int kq = 0; kq < 16; kq++){
      float av[4], bv[4];
#pragma unroll
      for (int i = 0; i < 4; i++) av[i] = As[kq][ty*4 + i];
#pragma unroll
      for (int j = 0; j < 4; j++) bv[j] = Bs[kq][tx*4 + j];
#pragma unroll
      for (int i = 0; i < 4; i++)
#pragma unroll
        for (int j = 0; j < 4; j++) acc[i][j] += av[i]*bv[j];
    }
    __syncthreads();
  }
#pragma unroll
  for (int i = 0; i < 4; i++){
    int m = bm + ty*4 + i;
#pragma unroll
    for (int j = 0; j < 4; j++){
      int n = bn + tx*4 + j;
      float v = acc[i][j] + bias[n];
      if (resid) v += resid[(size_t)m*ldc + n];
      stval(&Cc[(size_t)m*ldc + n], v);
    }
  }
}

__global__ __launch_bounds__(256) void ln_kernel(const float* __restrict__ Xin,
    const float* __restrict__ g, const float* __restrict__ b,
    u16* __restrict__ out, float eps){
  int t = blockIdx.x, c = threadIdx.x;
  float v = Xin[(size_t)t*256 + c];
  __shared__ float red[256];
  red[c] = v; __syncthreads();
  for (int s = 128; s > 0; s >>= 1){ if (c < s) red[c] += red[c + s]; __syncthreads(); }
  float mu = red[0] * (1.f/256.f);
  __syncthreads();
  float dv = v - mu;
  red[c] = dv*dv; __syncthreads();
  for (int s = 128; s > 0; s >>= 1){ if (c < s) red[c] += red[c + s]; __syncthreads(); }
  float var = red[0] * (1.f/256.f);
  out[(size_t)t*256 + c] = f2b(dv * rsqrtf(var + eps) * g[c] + b[c]);
}

// depthwise causal conv (K=4) + silu, bf16 in/out
__global__ __launch_bounds__(256) void conv_silu_kernel(const u16* __restrict__ Xc, int ldx, int C,
    const float* __restrict__ w, const float* __restrict__ bias, u16* __restrict__ Y){
  long long gid = (long long)blockIdx.x * 256 + threadIdx.x;   // T*C
  int c = (int)(gid % C); long long t = gid / C;
  int s = (int)(t & 255);
  float acc = bias[c];
#pragma unroll
  for (int j = 0; j < 4; j++){
    int so = s - 3 + j;
    if (so >= 0) acc += b2f(Xc[(size_t)(t - 3 + j)*ldx + c]) * w[j*C + c];
  }
  Y[(size_t)t*C + c] = f2b(acc / (1.f + expf(-acc)));
}

// ipre/fpre: gin=[q|k|v] (T x 1536) @ Wi/Wf (1536 x 4) -> (B,H,S)
__global__ __launch_bounds__(256) void gates_kernel(
    const u16* __restrict__ Q, const u16* __restrict__ Kb, const u16* __restrict__ V,
    const float* __restrict__ Wi, const float* __restrict__ bi,
    const float* __restrict__ Wf, const float* __restrict__ bf,
    float* __restrict__ IP, float* __restrict__ FP){
  int t = blockIdx.x; int tid = threadIdx.x;
  int o = tid & 7, seg = tid >> 3;            // o: 0-3 ipre, 4-7 fpre; seg 0..31
  int b = t >> 8, s = t & 255;
  int g = o & 3;
  const float* Wg = (o >= 4) ? Wf : Wi;
  float part = 0.f;
  for (int i = 0; i < 48; i++){
    int k = seg*48 + i;
    float gv;
    if (k < 512)       gv = b2f(Q [(size_t)t*512 + k]);
    else if (k < 1024) gv = b2f(Kb[(size_t)t*512 + k - 512]);
    else               gv = b2f(V [(size_t)t*512 + k - 1024]);
    part += gv * Wg[k*4 + g];
  }
  __shared__ float red[256];
  red[tid] = part; __syncthreads();
  if (tid < 8){
    float tot = 0.f;
    for (int ss = 0; ss < 32; ss++) tot += red[ss*8 + tid];
    int gg = tid & 3;
    if (tid < 4) IP[(b*4 + gg)*256 + s] = tot + bi[gg];
    else         FP[(b*4 + gg)*256 + s] = tot + bf[gg];
  }
}

// per (b,h): F=cumsum(logsigmoid(fpre)); G=ipre-F; M=cummax(G)
__global__ __launch_bounds__(256) void fscan_kernel(const float* __restrict__ IP,
    const float* __restrict__ FP, float* __restrict__ Fo, float* __restrict__ Go,
    float* __restrict__ Mo){
  int bh = blockIdx.x; int s = threadIdx.x;
  int idx = bh*256 + s;
  __shared__ float buf[256];
  float fp = FP[idx];
  float lfg = fminf(fp, 0.f) - log1pf(expf(-fabsf(fp)));
  float v = lfg;
  buf[s] = v; __syncthreads();
  for (int off = 1; off < 256; off <<= 1){
    float tv = (s >= off) ? buf[s - off] : 0.f;
    __syncthreads();
    v += tv; buf[s] = v;
    __syncthreads();
  }
  float Fv = v;
  float g = IP[idx] - Fv;
  float mv = g;
  buf[s] = mv; __syncthreads();
  for (int off = 1; off < 256; off <<= 1){
    float tv = (s >= off) ? buf[s - off] : -3.0e38f;
    __syncthreads();
    mv = fmaxf(mv, tv); buf[s] = mv;
    __syncthreads();
  }
  Fo[idx] = Fv; Go[idx] = g; Mo[idx] = mv;
}

// Fused mLSTM attention: per (bh, t-tile of 64) block.
//   Sc = (Q K^T / sqrt(128)) * exp(G[s]-M[t]) masked; rowsum -> rs
//   hh = (Sc @ V) / max(|rs|, exp(-(F+M)))
//   Y  = (headnorm(hh)*ng+nb + skip*a) * silu(zg)
__global__ __launch_bounds__(256) void attn_kernel(
    const u16* __restrict__ Q, const u16* __restrict__ Kb, const u16* __restrict__ V,
    const float* __restrict__ G, const float* __restrict__ Mx, const float* __restrict__ F,
    const u16* __restrict__ Ab, const u16* __restrict__ UPb,
    const float* __restrict__ ng, const float* __restrict__ nb,
    const float* __restrict__ skip, u16* __restrict__ Yb)
{
  int bh = blockIdx.y, b = bh >> 2, h = bh & 3;
  int tt = blockIdx.x, t0 = tt * 64;
  int tid = threadIdx.x;

  __shared__ u16 Qs[64][130];
  __shared__ u16 Ks[64][130];
  __shared__ u16 Vs[64][130];
  __shared__ u16 Cs[64][66];
  __shared__ float rs[64];

  for (int i = tid; i < 64*128; i += 256){
    int r = i >> 7, c = i & 127;
    Qs[r][c] = Q[((size_t)(b*256 + t0 + r))*512 + h*128 + c];
  }
  if (tid < 64) rs[tid] = 0.f;

  float acc[8][4] = {};
  const int cty = tid >> 5, ctx = tid & 31;
  const int ax = tid & 15, ay = tid >> 4;
  const float scale = 0.08838834764831845f;   // 1/sqrt(128)

  for (int ss = 0; ss <= tt; ss++){
    int s0 = ss * 64;
    __syncthreads();   // prior iteration's readers of Ks/Vs/Cs done
    for (int i = tid; i < 64*128; i += 256){
      int r = i >> 7, c = i & 127;
      size_t gidx = ((size_t)(b*256 + s0 + r))*512 + h*128 + c;
      Ks[r][c] = Kb[gidx];
      Vs[r][c] = V[gidx];
    }
    __syncthreads();
    // phase A: 64x64 QK^T, 16x16 threads, 4x4 each
    float sacc[4][4] = {};
    for (int k = 0; k < 128; k++){
      float av[4], bv[4];
#pragma unroll
      for (int i = 0; i < 4; i++) av[i] = b2f(Qs[ay*4 + i][k]);
#pragma unroll
      for (int j = 0; j < 4; j++) bv[j] = b2f(Ks[ax*4 + j][k]);
#pragma unroll
      for (int i = 0; i < 4; i++)
#pragma unroll
        for (int j = 0; j < 4; j++) sacc[i][j] += av[i]*bv[j];
    }
    float gv[4];
#pragma unroll
    for (int j = 0; j < 4; j++) gv[j] = G[bh*256 + s0 + ax*4 + j];
#pragma unroll
    for (int i = 0; i < 4; i++){
      int t = t0 + ay*4 + i;
      float mv = Mx[bh*256 + t];
      float rp = 0.f;
#pragma unroll
      for (int j = 0; j < 4; j++){
        int s = s0 + ax*4 + j;
        float cv2 = (s <= t) ? sacc[i][j]*scale*expf(gv[j] - mv) : 0.f;
        Cs[ay*4 + i][ax*4 + j] = f2b(cv2);
        rp += cv2;
      }
#pragma unroll
      for (int o = 8; o > 0; o >>= 1) rp += __shfl_xor(rp, o, 16);
      if (ax == 0) rs[ay*4 + i] += rp;
    }
    __syncthreads();
    // phase B: acc(64x128) += Cs(64x64) @ Vs(64x128); 8 rows x 4 cols / thread
    for (int s = 0; s < 64; s++){
      float vv[4];
#pragma unroll
      for (int j = 0; j < 4; j++) vv[j] = b2f(Vs[s][ctx*4 + j]);
#pragma unroll
      for (int i = 0; i < 8; i++){
        float cw = b2f(Cs[cty*8 + i][s]);
#pragma unroll
        for (int j = 0; j < 4; j++) acc[i][j] += cw*vv[j];
      }
    }
  }
  __syncthreads();
  // epilogue: normalize, headnorm over 128 dims (32 threads per row), gate
#pragma unroll
  for (int i = 0; i < 8; i++){
    int r = cty*8 + i, t = t0 + r;
    float Fv = F[bh*256 + t], Mv = Mx[bh*256 + t];
    float nrm = fmaxf(fabsf(rs[r]), expf(-(Fv + Mv)));
    float inv = 1.f / nrm;
    float v[4];
#pragma unroll
    for (int j = 0; j < 4; j++) v[j] = acc[i][j]*inv;
    float su = v[0] + v[1] + v[2] + v[3];
#pragma unroll
    for (int o = 16; o > 0; o >>= 1) su += __shfl_xor(su, o, 32);
    float mu = su * (1.f/128.f);
    float sq = 0.f;
#pragma unroll
    for (int j = 0; j < 4; j++){ v[j] -= mu; sq += v[j]*v[j]; }
#pragma unroll
    for (int o = 16; o > 0; o >>= 1) sq += __shfl_xor(sq, o, 32);
    float rstd = rsqrtf(sq * (1.f/128.f) + 1e-6f);
#pragma unroll
    for (int j = 0; j < 4; j++){
      int c = h*128 + ctx*4 + j;
      float hv = v[j]*rstd*ng[c] + nb[c];
      float av = b2f(Ab[(size_t)t*512 + c]);
      float zg = b2f(UPb[(size_t)t*1024 + 512 + c]);
      float sz = zg / (1.f + expf(-zg));
      Yb[(size_t)t*512 + c] = f2b((hv + skip[c]*av)*sz);
    }
  }
}

// sLSTM recurrence: one wave per (b,h); R in LDS bf16; states fp32 in regs
__global__ __launch_bounds__(64) void scan_kernel(
    const float* __restrict__ IT, const float* __restrict__ FT,
    const float* __restrict__ ZT, const float* __restrict__ OT,
    const float* __restrict__ Ri, const float* __restrict__ Rf,
    const float* __restrict__ Rz, const float* __restrict__ Ro,
    const float* __restrict__ sng, const float* __restrict__ snb,
    float* __restrict__ Xr){
  int bh = blockIdx.x; int b = bh >> 2, h = bh & 3;
  int e = threadIdx.x;
  __shared__ u16 Rl[4][64][64];
  const float* Rp0 = Ri + h*4096; const float* Rp1 = Rf + h*4096;
  const float* Rp2 = Rz + h*4096; const float* Rp3 = Ro + h*4096;
  for (int d = 0; d < 64; d++){
    Rl[0][d][e] = f2b(Rp0[d*64 + e]);
    Rl[1][d][e] = f2b(Rp1[d*64 + e]);
    Rl[2][d][e] = f2b(Rp2[d*64 + e]);
    Rl[3][d][e] = f2b(Rp3[d*64 + e]);
  }
  __syncthreads();
  float gw = sng[h*64 + e], bw = snb[h*64 + e];
  float hS = 0.f, cS = 0.f, nS = 0.f, mS = 0.f;
  for (int s = 0; s < 256; s++){
    size_t row = ((size_t)(b*256 + s))*256 + h*64 + e;
    float i0 = IT[row], f0 = FT[row], z0 = ZT[row], o0 = OT[row];
    float ri = 0.f, rf = 0.f, rz = 0.f, ro = 0.f;
#pragma unroll
    for (int d = 0; d < 64; d++){
      float hd = __builtin_bit_cast(float,
          __builtin_amdgcn_readlane(__builtin_bit_cast(int, hS), d));
      ri += hd * b2f(Rl[0][d][e]);
      rf += hd * b2f(Rl[1][d][e]);
      rz += hd * b2f(Rl[2][d][e]);
      ro += hd * b2f(Rl[3][d][e]);
    }
    float ip = i0 + ri;
    float fp = f0 + rf;
    float zp = tanhf(z0 + rz);
    float op = 1.f / (1.f + expf(-(o0 + ro)));
    float mn = fmaxf(fp + mS, ip);
    float ig = expf(ip - mn);
    float fg = expf(fp + mS - mn);
    cS = fg*cS + ig*zp;
    nS = fg*nS + ig;
    mS = mn;
    hS = op * cS / nS;
    float su = hS;
#pragma unroll
    for (int o = 32; o > 0; o >>= 1) su += __shfl_xor(su, o, 64);
    float mu = su * (1.f/64.f);
    float dv = hS - mu;
    float sq = dv*dv;
#pragma unroll
    for (int o = 32; o > 0; o >>= 1) sq += __shfl_xor(sq, o, 64);
    float nv = dv * rsqrtf(sq * (1.f/64.f) + 1e-6f) * gw + bw;
    Xr[row] += nv;
  }
}

// FFN activation: P = gelu_tanh(g) * u
__global__ __launch_bounds__(256) void ffn_act_kernel(const u16* __restrict__ GU,
                                                      u16* __restrict__ P){
  long long gid = (long long)blockIdx.x * 256 + threadIdx.x;   // T*352
  int j = (int)(gid % 352); long long t = gid / 352;
  float g = b2f(GU[(size_t)t*704 + j]);
  float u = b2f(GU[(size_t)t*704 + 352 + j]);
  float inner = 0.7978845608028654f * (g + 0.044715f*g*g*g);
  float gel = 0.5f * g * (1.f + tanhf(inner));
  P[(size_t)t*352 + j] = f2b(gel * u);
}

// output head: relu(last@W1+b1)@W2+b2, write in detected dtype
__global__ __launch_bounds__(64) void head_kernel(const float* __restrict__ X,
    const float* __restrict__ W1, const float* __restrict__ b1,
    const float* __restrict__ W2, const float* __restrict__ b2,
    void* out, const int* __restrict__ flag){
  int b = blockIdx.x, j = threadIdx.x;
  __shared__ float L[256];
  __shared__ float H1[64];
  for (int i = j; i < 256; i += 64) L[i] = X[((size_t)(b*256 + 255))*256 + i];
  __syncthreads();
  float acc = b1[j];
  for (int d = 0; d < 256; d++) acc += L[d] * W1[d*64 + j];
  H1[j] = fmaxf(acc, 0.f);
  __syncthreads();
  if (j < 3){
    float o = b2[j];
    for (int k2 = 0; k2 < 64; k2++) o += H1[k2] * W2[k2*3 + j];
    if (*flag) ((u16*)out)[b*3 + j] = f2b(o);
    else       ((float*)out)[b*3 + j] = o;
  }
}

// ----------------------------- launch --------------------------------------
extern "C" void kernel_launch(void* const* d_in, const int* in_sizes, int n_in,
                              void* d_out, int out_size, void* d_ws, size_t ws_size,
                              hipStream_t stream)
{
  // sanity guard: wrong harness assumptions -> do nothing (graceful fail)
  if (n_in != IN_N) return;
  for (int i = 0; i < IN_N; i++) if ((long long)in_sizes[i] != IN_SIZES[i]) return;
  if (ws_size < (size_t)WS_END * 4) return;
  if (out_size != 384) return;

  float* ws = (float*)d_ws;
  float* cv = ws;
  auto cvp = [&](int i){ return cv + CVOFF.off[i]; };

  int*   flag = (int*)(ws + OFF_FLAG);
  float* IP   = ws + OFF_IP;
  float* FP   = ws + OFF_FP;
  float* Fb   = ws + OFF_F;
  float* Gb   = ws + OFF_G;
  float* Mb   = ws + OFF_M;
  float* X    = ws + OFF_X;
  u16*   XNb  = (u16*)(ws + OFF_XN);
  u16*   UPb  = (u16*)(ws + OFF_UP);
  u16*   Ab   = (u16*)(ws + OFF_A);
  u16*   Qb   = (u16*)(ws + OFF_Q);
  u16*   Kbb  = (u16*)(ws + OFF_K);
  u16*   Vb   = (u16*)(ws + OFF_V);
  // overlays (lifetimes disjoint):
  float* CAT = ws + OFF_V;     // dead before V written
  u16*   Yb  = Qb;             // Y overlays Q (Q dead after attn; written only by its own block's epilogue slice)
  u16*   ACb = Ab;             // sLSTM conv out overlays a
  float* ITf = ws + OFF_K;     // K dead after attn
  float* FTf = ws + OFF_V;     // V dead after attn
  float* ZTf = ws + OFF_Q;     // Y dead after Wdown gemm
  float* OTf = ws + OFF_UP;    // UP dead after attn epilogue
  u16*   GUb = UPb;            // OT dead after scan
  u16*   Pb  = Ab;             // AC dead after IT/FT gemms

  InPtrs ptrs;
  for (int i = 0; i < IN_N; i++) ptrs.p[i] = d_in[i];

  const int M = 32768;
  detect_kernel<<<1, 64, 0, stream>>>(d_in[7], flag);
  int cvblocks = (int)((CV_TOTAL + 255) / 256);
  convert_kernel<<<cvblocks, 256, 0, stream>>>(ptrs, cv, flag);
  cat_kernel<<<5120, 256, 0, stream>>>(cvp(0), (const int*)d_in[1], (const int*)d_in[2],
                                       cvp(3), cvp(4), CAT);
  // x = cat @ W_in + b_in
  gemm_kernel<float, float><<<dim3(4, 512), 256, 0, stream>>>(CAT, 40, cvp(5), cvp(6),
      X, 256, nullptr, M, 256, 40);
  // ---- mLSTM block ----
  ln_kernel<<<M, 256, 0, stream>>>(X, cvp(7), cvp(8), XNb, 1e-5f);
  gemm_kernel<u16, u16><<<dim3(16, 512), 256, 0, stream>>>(XNb, 256, cvp(9), cvp(10),
      UPb, 1024, nullptr, M, 1024, 256);
  conv_silu_kernel<<<65536, 256, 0, stream>>>(UPb, 1024, 512, cvp(11), cvp(12), Ab);
  gemm_kernel<u16, u16><<<dim3(8, 512), 256, 0, stream>>>(Ab, 512, cvp(13), cvp(14),
      Qb, 512, nullptr, M, 512, 512);
  gemm_kernel<u16, u16><<<dim3(8, 512), 256, 0, stream>>>(Ab, 512, cvp(15), cvp(16),
      Kbb, 512, nullptr, M, 512, 512);
  gemm_kernel<u16, u16><<<dim3(8, 512), 256, 0, stream>>>(UPb, 1024, cvp(17), cvp(18),
      Vb, 512, nullptr, M, 512, 512);
  gates_kernel<<<M, 256, 0, stream>>>(Qb, Kbb, Vb, cvp(19), cvp(20), cvp(21), cvp(22), IP, FP);
  fscan_kernel<<<512, 256, 0, stream>>>(IP, FP, Fb, Gb, Mb);
  attn_kernel<<<dim3(4, 512), 256, 0, stream>>>(Qb, Kbb, Vb, Gb, Mb, Fb,
      Ab, UPb, cvp(24), cvp(25), cvp(23), Yb);
  gemm_kernel<u16, float><<<dim3(4, 512), 256, 0, stream>>>(Yb, 512, cvp(26), cvp(27),
      X, 256, X, M, 256, 512);
  // ---- sLSTM block ----
  ln_kernel<<<M, 256, 0, stream>>>(X, cvp(28), cvp(29), XNb, 1e-5f);
  conv_silu_kernel<<<32768, 256, 0, stream>>>(XNb, 256, 256, cvp(30), cvp(31), ACb);
  gemm_kernel<u16, float><<<dim3(4, 512), 256, 0, stream>>>(ACb, 256, cvp(32), cvp(33),
      ITf, 256, nullptr, M, 256, 256);
  gemm_kernel<u16, float><<<dim3(4, 512), 256, 0, stream>>>(ACb, 256, cvp(34), cvp(35),
      FTf, 256, nullptr, M, 256, 256);
  gemm_kernel<u16, float><<<dim3(4, 512), 256, 0, stream>>>(XNb, 256, cvp(36), cvp(37),
      ZTf, 256, nullptr, M, 256, 256);
  gemm_kernel<u16, float><<<dim3(4, 512), 256, 0, stream>>>(XNb, 256, cvp(38), cvp(39),
      OTf, 256, nullptr, M, 256, 256);
  scan_kernel<<<512, 64, 0, stream>>>(ITf, FTf, ZTf, OTf, cvp(40), cvp(41), cvp(42), cvp(43),
      cvp(44), cvp(45), X);
  // ---- FFN ----
  ln_kernel<<<M, 256, 0, stream>>>(X, cvp(46), cvp(47), XNb, 1e-5f);
  gemm_kernel<u16, u16><<<dim3(11, 512), 256, 0, stream>>>(XNb, 256, cvp(48), cvp(49),
      GUb, 704, nullptr, M, 704, 256);
  ffn_act_kernel<<<45056, 256, 0, stream>>>(GUb, Pb);
  gemm_kernel<u16, float><<<dim3(4, 512), 256, 0, stream>>>(Pb, 352, cvp(50), cvp(51),
      X, 256, X, M, 256, 352);
  // ---- head ----
  head_kernel<<<128, 64, 0, stream>>>(X, cvp(52), cvp(53), cvp(54), cvp(55), d_out, flag);
}

// Round 4
// 1646.081 us; speedup vs baseline: 2.1043x; 2.1043x over previous
//
#include <hip/hip_runtime.h>
#include <cstdint>
#include <cstddef>

// ---------------------------------------------------------------------------
// Model_xLSTM: B=128 S=256 NF=32 E=4 D=256 H=4 DI=512 DHM=128 DHS=64 K=4 FF=352
// Round 3: same compute as R2 (MFMA GEMM + fused MFMA attention + 4-wave scan)
// but transposed weights are built directly from the input buffers (no fp32 cv
// copy for them), shrinking the ws requirement to ~250 MiB (< 256 MiB guard
// trip that stubbed R2).
// ---------------------------------------------------------------------------

using u16 = unsigned short;
using u32 = unsigned int;

typedef __attribute__((ext_vector_type(8))) short short8;
typedef __attribute__((ext_vector_type(8))) unsigned short ushort8v;
typedef __attribute__((ext_vector_type(4))) float float4v;

#define DEVINL __device__ __forceinline__

DEVINL float b2f(u16 u){ u32 x = ((u32)u) << 16; return __builtin_bit_cast(float, x); }
DEVINL u16 f2b(float f){
  u32 x = __builtin_bit_cast(u32, f);
  u32 r = x + 0x7FFFu + ((x >> 16) & 1u);   // RTNE
  return (u16)(r >> 16);
}
DEVINL float ldval(float x){ return x; }
DEVINL float ldval(u16 x){ return b2f(x); }
DEVINL void stval(float* p, float v){ *p = v; }
DEVINL void stval(u16* p, float v){ *p = f2b(v); }

// ----------------------------- input table ---------------------------------
constexpr int IN_N = 56;
constexpr long long IN_SIZES[IN_N] = {
  1048576, 128, 128, 404, 28, 10240, 256, 256, 256,
  262144, 1024, 2048, 512,
  262144, 512, 262144, 512, 262144, 512,
  6144, 4, 6144, 4,
  512, 512, 512, 131072, 256,
  256, 256, 1024, 256,
  65536, 256, 65536, 256, 65536, 256, 65536, 256,
  16384, 16384, 16384, 16384,
  256, 256,
  256, 256, 180224, 704, 90112, 256,
  16384, 64, 192, 3 };

// inputs that are ONLY consumed as transposed bf16 weights (no fp32 cv copy)
constexpr bool is_wt_input(int i){
  return i==9 || i==13 || i==15 || i==17 || i==26 || i==32 || i==34 || i==36
      || i==38 || i==48 || i==50;
}

struct CvOff { long long off[IN_N+1]; };
constexpr CvOff make_off(){
  CvOff o{};
  long long a = 0;
  for (int i = 0; i < IN_N; i++){
    o.off[i] = a;
    long long s = IN_SIZES[i];
    if (i == 1 || i == 2 || is_wt_input(i)) s = 0;
    a += s;
  }
  o.off[IN_N] = a;
  return o;
}
constexpr CvOff CVOFF = make_off();
constexpr long long CV_TOTAL = CVOFF.off[IN_N];

// transposed-weight table
constexpr int WT_NW = 11;
constexpr int WTB_IN[WT_NW] = {9, 13, 15, 17, 26, 32, 34, 36, 38, 48, 50};
constexpr int WTB_K[WT_NW]  = {256,512,512,512,512,256,256,256,256,256,352};
constexpr int WTB_N[WT_NW]  = {1024,512,512,512,256,256,256,256,256,704,256};
constexpr long long WTO[WT_NW+1] = {0, 262144, 524288, 786432, 1048576, 1179648,
  1245184, 1310720, 1376256, 1441792, 1622016, 1712128};
constexpr long long WT_ELEMS = WTO[WT_NW];                // u16 elements

// ----------------------------- ws layout (float units) ---------------------
constexpr long long alignup(long long x){ return ((x + 255) / 256) * 256; }
constexpr long long TOK = 32768;            // B*S
constexpr long long OFF_FLAG = alignup(CV_TOTAL);
constexpr long long OFF_IP  = OFF_FLAG + 64;
constexpr long long OFF_FP  = OFF_IP  + 131072;
constexpr long long OFF_F   = OFF_FP  + 131072;
constexpr long long OFF_G   = OFF_F   + 131072;
constexpr long long OFF_M   = OFF_G   + 131072;
constexpr long long OFF_X   = OFF_M   + 131072;           // T x 256 fp32
constexpr long long OFF_XN  = OFF_X   + TOK*256;          // T x 256 bf16
constexpr long long OFF_UP  = OFF_XN  + TOK*128;          // T x 1024 bf16 (xm|zg)
constexpr long long OFF_A   = OFF_UP  + TOK*512;          // T x 512 bf16 (a / AC / P)
constexpr long long OFF_Q   = OFF_A   + TOK*256;          // T x 512 bf16 (q / Y / ZT fp32)
constexpr long long OFF_K   = OFF_Q   + TOK*256;          // T x 512 bf16 (k / IT fp32)
constexpr long long OFF_V   = OFF_K   + TOK*256;          // T x 512 bf16 (CAT / v / FT fp32)
constexpr long long OFF_WT  = OFF_V   + TOK*256;          // transposed bf16 weights
constexpr long long WS_END  = OFF_WT  + WT_ELEMS/2 + 256; // ~65.6M floats ~ 250 MiB

// ----------------------------- kernels -------------------------------------

__global__ void detect_kernel(const void* mlng, int* flag){
  if (threadIdx.x == 0){
    u32 u = *(const u32*)mlng;
    *flag = (u == 0x3F803F80u) ? 1 : 0;
  }
}

struct InPtrs { const void* p[IN_N]; };

__global__ __launch_bounds__(256) void convert_kernel(InPtrs ptrs, float* __restrict__ cv,
                                                      const int* __restrict__ flag){
  long long gid = (long long)blockIdx.x * 256 + threadIdx.x;
  if (gid >= CV_TOTAL) return;
  int seg = 0;
#pragma unroll
  for (int i = 1; i < IN_N; i++) seg += (gid >= CVOFF.off[i]) ? 1 : 0;
  // skip-inputs have zero-length segments: gid never lands in them
  long long local = gid - CVOFF.off[seg];
  float v;
  if (*flag) v = b2f(((const u16*)ptrs.p[seg])[local]);
  else       v = ((const float*)ptrs.p[seg])[local];
  cv[gid] = v;
}

// W[K][N] (fp32 or bf16 input) -> WT[N][K] bf16; 32x32 LDS tiles.
__global__ __launch_bounds__(256) void wtrans_kernel(InPtrs ptrs, u16* __restrict__ WTb,
                                                     const int* __restrict__ flag){
  int wz = blockIdx.z;
  int K = WTB_K[wz], N = WTB_N[wz];
  int n0 = blockIdx.x * 32, k0 = blockIdx.y * 32;
  if (n0 >= N || k0 >= K) return;
  const void* W = ptrs.p[WTB_IN[wz]];
  u16* WT = WTb + WTO[wz];
  __shared__ u16 tile[32][34];
  int tx = threadIdx.x & 31, ty = threadIdx.x >> 5;
  bool bf = (*flag != 0);
#pragma unroll
  for (int i = 0; i < 4; i++){
    size_t src = (size_t)(k0 + ty + i*8)*N + n0 + tx;
    tile[ty + i*8][tx] = bf ? ((const u16*)W)[src] : f2b(((const float*)W)[src]);
  }
  __syncthreads();
#pragma unroll
  for (int i = 0; i < 4; i++)
    WT[(size_t)(n0 + ty + i*8)*K + k0 + tx] = tile[tx][ty + i*8];
}

__global__ __launch_bounds__(256) void cat_kernel(const float* __restrict__ xs,
    const int* __restrict__ xe, const int* __restrict__ xp,
    const float* __restrict__ ee, const float* __restrict__ ep,
    float* __restrict__ CAT){
  int gid = blockIdx.x * 256 + threadIdx.x;   // T*40
  int c = gid % 40; int t = gid / 40; int b = t >> 8;
  float v;
  if (c < 32)      v = xs[(size_t)t*32 + c];
  else if (c < 36) v = ee[xe[b]*4 + (c - 32)];
  else             v = ep[xp[b]*4 + (c - 36)];
  CAT[(size_t)t*40 + c] = v;
}

// SIMT GEMM kept for W_in (K=40, fp32 in/out)
template<typename TA, typename TC>
__global__ __launch_bounds__(256) void gemm_kernel(
    const TA* __restrict__ A, int lda,
    const float* __restrict__ Wm, const float* __restrict__ bias,
    TC* __restrict__ Cc, int ldc, const float* __restrict__ resid,
    int M, int N, int K)
{
  __shared__ float As[16][68];
  __shared__ float Bs[16][68];
  const int bm = blockIdx.y * 64, bn = blockIdx.x * 64;
  const int tid = threadIdx.x, tx = tid & 15, ty = tid >> 4;
  float acc[4][4] = {};
  for (int k0 = 0; k0 < K; k0 += 16){
#pragma unroll
    for (int i = 0; i < 4; i++){
      int idx = tid + i*256;
      int m = idx >> 4, kq = idx & 15;
      As[kq][m] = (k0 + kq < K) ? ldval(A[(size_t)(bm + m)*lda + k0 + kq]) : 0.f;
      int kk = idx >> 6, n = idx & 63;
      Bs[kk][n] = (k0 + kk < K) ? Wm[(size_t)(k0 + kk)*N + bn + n] : 0.f;
    }
    __syncthreads();
#pragma unroll
    for (int kq = 0; kq < 16; kq++){
      float av[4], bv[4];
#pragma unroll
      for (int i = 0; i < 4; i++) av[i] = As[kq][ty*4 + i];
#pragma unroll
      for (int j = 0; j < 4; j++) bv[j] = Bs[kq][tx*4 + j];
#pragma unroll
      for (int i = 0; i < 4; i++)
#pragma unroll
        for (int j = 0; j < 4; j++) acc[i][j] += av[i]*bv[j];
    }
    __syncthreads();
  }
#pragma unroll
  for (int i = 0; i < 4; i++){
    int m = bm + ty*4 + i;
#pragma unroll
    for (int j = 0; j < 4; j++){
      int n = bn + tx*4 + j;
      float v = acc[i][j] + bias[n];
      if (resid) v += resid[(size_t)m*ldc + n];
      stval(&Cc[(size_t)m*ldc + n], v);
    }
  }
}

// MFMA GEMM: C[M,N] = A[M,K](bf16) @ W[K,N] + bias (+resid), WT = W^T bf16 [N][K]
// 128x128 macro tile, 4 waves in 2x2, each 64x64 via 4x4 mfma_16x16x32.
template<typename TC>
__global__ __launch_bounds__(256) void gemm_mfma(
    const u16* __restrict__ A, int lda,
    const u16* __restrict__ WT,
    const float* __restrict__ bias,
    TC* __restrict__ Cc, int ldc, const float* __restrict__ resid,
    int N, int K)
{
  __shared__ alignas(16) u16 As[128*40];
  __shared__ alignas(16) u16 Bs[128*40];
  const int bm = blockIdx.y * 128, bn = blockIdx.x * 128;
  const int tid = threadIdx.x;
  const int w = tid >> 6, lane = tid & 63, lm = lane & 15, q = lane >> 4;
  const int wm = w >> 1, wn = w & 1;
  float4v acc[4][4] = {};
  for (int k0 = 0; k0 < K; k0 += 32){
    __syncthreads();
#pragma unroll
    for (int c = tid; c < 512; c += 256){
      int r = c >> 2, ch = c & 3;
      *(uint4*)&As[r*40 + ch*8] = *(const uint4*)&A[(size_t)(bm + r)*lda + k0 + ch*8];
      int n = bn + r;
      uint4 bv = {0u,0u,0u,0u};
      if (n < N) bv = *(const uint4*)&WT[(size_t)n*K + k0 + ch*8];
      *(uint4*)&Bs[r*40 + ch*8] = bv;
    }
    __syncthreads();
    short8 a[4], b[4];
#pragma unroll
    for (int i = 0; i < 4; i++)
      a[i] = *(const short8*)&As[(wm*64 + i*16 + lm)*40 + q*8];
#pragma unroll
    for (int j = 0; j < 4; j++)
      b[j] = *(const short8*)&Bs[(wn*64 + j*16 + lm)*40 + q*8];
#pragma unroll
    for (int i = 0; i < 4; i++)
#pragma unroll
      for (int j = 0; j < 4; j++)
        acc[i][j] = __builtin_amdgcn_mfma_f32_16x16x32_bf16(a[i], b[j], acc[i][j], 0, 0, 0);
  }
#pragma unroll
  for (int i = 0; i < 4; i++){
#pragma unroll
    for (int j = 0; j < 4; j++){
      int col = bn + wn*64 + j*16 + lm;
      if (col < N){
#pragma unroll
        for (int r = 0; r < 4; r++){
          int row = bm + wm*64 + i*16 + q*4 + r;
          float v = acc[i][j][r] + bias[col];
          if (resid) v += resid[(size_t)row*ldc + col];
          stval(&Cc[(size_t)row*ldc + col], v);
        }
      }
    }
  }
}

__global__ __launch_bounds__(256) void ln_kernel(const float* __restrict__ Xin,
    const float* __restrict__ g, const float* __restrict__ b,
    u16* __restrict__ out, float eps){
  int t = blockIdx.x, c = threadIdx.x;
  float v = Xin[(size_t)t*256 + c];
  __shared__ float red[256];
  red[c] = v; __syncthreads();
  for (int s = 128; s > 0; s >>= 1){ if (c < s) red[c] += red[c + s]; __syncthreads(); }
  float mu = red[0] * (1.f/256.f);
  __syncthreads();
  float dv = v - mu;
  red[c] = dv*dv; __syncthreads();
  for (int s = 128; s > 0; s >>= 1){ if (c < s) red[c] += red[c + s]; __syncthreads(); }
  float var = red[0] * (1.f/256.f);
  out[(size_t)t*256 + c] = f2b(dv * rsqrtf(var + eps) * g[c] + b[c]);
}

// depthwise causal conv (K=4) + silu, bf16 in/out
__global__ __launch_bounds__(256) void conv_silu_kernel(const u16* __restrict__ Xc, int ldx, int C,
    const float* __restrict__ w, const float* __restrict__ bias, u16* __restrict__ Y){
  long long gid = (long long)blockIdx.x * 256 + threadIdx.x;   // T*C
  int c = (int)(gid % C); long long t = gid / C;
  int s = (int)(t & 255);
  float acc = bias[c];
#pragma unroll
  for (int j = 0; j < 4; j++){
    int so = s - 3 + j;
    if (so >= 0) acc += b2f(Xc[(size_t)(t - 3 + j)*ldx + c]) * w[j*C + c];
  }
  Y[(size_t)t*C + c] = f2b(acc / (1.f + expf(-acc)));
}

// ipre/fpre: gin=[q|k|v] (T x 1536) @ Wi/Wf (1536 x 4) -> (B,H,S)
__global__ __launch_bounds__(256) void gates_kernel(
    const u16* __restrict__ Q, const u16* __restrict__ Kb, const u16* __restrict__ V,
    const float* __restrict__ Wi, const float* __restrict__ bi,
    const float* __restrict__ Wf, const float* __restrict__ bf,
    float* __restrict__ IP, float* __restrict__ FP){
  int t = blockIdx.x; int tid = threadIdx.x;
  int o = tid & 7, seg = tid >> 3;
  int b = t >> 8, s = t & 255;
  int g = o & 3;
  const float* Wg = (o >= 4) ? Wf : Wi;
  float part = 0.f;
  for (int i = 0; i < 48; i++){
    int k = seg*48 + i;
    float gv;
    if (k < 512)       gv = b2f(Q [(size_t)t*512 + k]);
    else if (k < 1024) gv = b2f(Kb[(size_t)t*512 + k - 512]);
    else               gv = b2f(V [(size_t)t*512 + k - 1024]);
    part += gv * Wg[k*4 + g];
  }
  __shared__ float red[256];
  red[tid] = part; __syncthreads();
  if (tid < 8){
    float tot = 0.f;
    for (int ss = 0; ss < 32; ss++) tot += red[ss*8 + tid];
    int gg = tid & 3;
    if (tid < 4) IP[(b*4 + gg)*256 + s] = tot + bi[gg];
    else         FP[(b*4 + gg)*256 + s] = tot + bf[gg];
  }
}

// per (b,h): F=cumsum(logsigmoid(fpre)); G=ipre-F; M=cummax(G)
__global__ __launch_bounds__(256) void fscan_kernel(const float* __restrict__ IP,
    const float* __restrict__ FP, float* __restrict__ Fo, float* __restrict__ Go,
    float* __restrict__ Mo){
  int bh = blockIdx.x; int s = threadIdx.x;
  int idx = bh*256 + s;
  __shared__ float buf[256];
  float fp = FP[idx];
  float lfg = fminf(fp, 0.f) - log1pf(expf(-fabsf(fp)));
  float v = lfg;
  buf[s] = v; __syncthreads();
  for (int off = 1; off < 256; off <<= 1){
    float tv = (s >= off) ? buf[s - off] : 0.f;
    __syncthreads();
    v += tv; buf[s] = v;
    __syncthreads();
  }
  float Fv = v;
  float g = IP[idx] - Fv;
  float mv = g;
  buf[s] = mv; __syncthreads();
  for (int off = 1; off < 256; off <<= 1){
    float tv = (s >= off) ? buf[s - off] : -3.0e38f;
    __syncthreads();
    mv = fmaxf(mv, tv); buf[s] = mv;
    __syncthreads();
  }
  Fo[idx] = Fv; Go[idx] = g; Mo[idx] = mv;
}

// Fused MFMA mLSTM attention. Block = (bh, t-tile of 64), 256 threads / 4 waves.
__global__ __launch_bounds__(256) void attn_kernel(
    const u16* __restrict__ Q, const u16* __restrict__ Kb, const u16* __restrict__ V,
    const float* __restrict__ G, const float* __restrict__ Mx, const float* __restrict__ F,
    const u16* __restrict__ Ab, const u16* __restrict__ UPb,
    const float* __restrict__ ng, const float* __restrict__ nb,
    const float* __restrict__ skip, u16* __restrict__ Yb)
{
  int bh = blockIdx.y, b = bh >> 2, h = bh & 3;
  int tt = blockIdx.x, t0 = tt * 64;
  int tid = threadIdx.x;
  int w = tid >> 6, lane = tid & 63, lm = lane & 15, q = lane >> 4;
  int gbase = bh * 256;

  __shared__ alignas(16) u16 Qs[64*136];
  __shared__ alignas(16) u16 Ks[64*136];
  __shared__ alignas(16) u16 Vt[128*72];
  __shared__ alignas(16) u16 Ps[64*72];
  __shared__ float rs[64];

#pragma unroll
  for (int c = tid; c < 1024; c += 256){
    int r = c >> 4, ch = c & 15;
    *(uint4*)&Qs[r*136 + ch*8] =
      *(const uint4*)&Q[((size_t)(b*256 + t0 + r))*512 + h*128 + ch*8];
  }
  if (tid < 64) rs[tid] = 0.f;

  float mrow[4];
#pragma unroll
  for (int r = 0; r < 4; r++) mrow[r] = Mx[gbase + t0 + w*16 + q*4 + r];

  float4v acc2[8] = {};          // t-strip x 128 d
  const float scale = 0.08838834764831845f;   // 1/sqrt(128)

  for (int ss = 0; ss <= tt; ss++){
    int s0 = ss * 64;
    __syncthreads();
#pragma unroll
    for (int c = tid; c < 1024; c += 256){
      int r = c >> 4, ch = c & 15;
      *(uint4*)&Ks[r*136 + ch*8] =
        *(const uint4*)&Kb[((size_t)(b*256 + s0 + r))*512 + h*128 + ch*8];
    }
#pragma unroll
    for (int c = tid; c < 1024; c += 256){
      int sl = c & 63, db = c >> 6;
      ushort8v v = *(const ushort8v*)&V[((size_t)(b*256 + s0 + sl))*512 + h*128 + db*8];
#pragma unroll
      for (int j = 0; j < 8; j++) Vt[(db*8 + j)*72 + sl] = v[j];
    }
    __syncthreads();
    // --- QK^T ---
    float4v sacc[4] = {};
#pragma unroll
    for (int k0 = 0; k0 < 128; k0 += 32){
      short8 a = *(const short8*)&Qs[(w*16 + lm)*136 + k0 + q*8];
#pragma unroll
      for (int j = 0; j < 4; j++){
        short8 bb = *(const short8*)&Ks[(j*16 + lm)*136 + k0 + q*8];
        sacc[j] = __builtin_amdgcn_mfma_f32_16x16x32_bf16(a, bb, sacc[j], 0, 0, 0);
      }
    }
    // --- decay + mask + Ps + rowsum ---
    float rp[4] = {0.f, 0.f, 0.f, 0.f};
#pragma unroll
    for (int j = 0; j < 4; j++){
      int scol = s0 + j*16 + lm;
      float gq = G[gbase + scol];
#pragma unroll
      for (int r = 0; r < 4; r++){
        int trow = t0 + w*16 + q*4 + r;
        float cval = (scol <= trow) ? sacc[j][r]*scale*__expf(gq - mrow[r]) : 0.f;
        Ps[(w*16 + q*4 + r)*72 + j*16 + lm] = f2b(cval);
        rp[r] += cval;
      }
    }
#pragma unroll
    for (int r = 0; r < 4; r++){
#pragma unroll
      for (int m = 1; m < 16; m <<= 1) rp[r] += __shfl_xor(rp[r], m, 16);
      if (lm == 0) rs[w*16 + q*4 + r] += rp[r];
    }
    // --- PV (wave-local Ps rows; Vt synced above) ---
#pragma unroll
    for (int k0 = 0; k0 < 64; k0 += 32){
      short8 a = *(const short8*)&Ps[(w*16 + lm)*72 + k0 + q*8];
#pragma unroll
      for (int jd = 0; jd < 8; jd++){
        short8 bb = *(const short8*)&Vt[(jd*16 + lm)*72 + k0 + q*8];
        acc2[jd] = __builtin_amdgcn_mfma_f32_16x16x32_bf16(a, bb, acc2[jd], 0, 0, 0);
      }
    }
  }
  __syncthreads();
  // --- epilogue ---
#pragma unroll
  for (int r = 0; r < 4; r++){
    int rl = w*16 + q*4 + r;
    int t = t0 + rl;
    float Fv = F[gbase + t];
    float nrm = fmaxf(fabsf(rs[rl]), __expf(-(Fv + mrow[r])));
    float inv = 1.f / nrm;
    float vv[8];
    float su = 0.f;
#pragma unroll
    for (int jd = 0; jd < 8; jd++){ vv[jd] = acc2[jd][r]*inv; su += vv[jd]; }
#pragma unroll
    for (int m = 1; m < 16; m <<= 1) su += __shfl_xor(su, m, 16);
    float mu = su * (1.f/128.f);
    float sq = 0.f;
#pragma unroll
    for (int jd = 0; jd < 8; jd++){ vv[jd] -= mu; sq += vv[jd]*vv[jd]; }
#pragma unroll
    for (int m = 1; m < 16; m <<= 1) sq += __shfl_xor(sq, m, 16);
    float rstd = rsqrtf(sq * (1.f/128.f) + 1e-6f);
#pragma unroll
    for (int jd = 0; jd < 8; jd++){
      int c = h*128 + jd*16 + lm;
      float hv = vv[jd]*rstd*ng[c] + nb[c];
      float av = b2f(Ab[(size_t)t*512 + c]);
      float zg = b2f(UPb[(size_t)t*1024 + 512 + c]);
      float sz = zg / (1.f + __expf(-zg));
      Yb[(size_t)t*512 + c] = f2b((hv + skip[c]*av)*sz);
    }
  }
}

// sLSTM recurrence: block = (b,h), 256 threads / 4 waves, wave g owns gate g.
__global__ __launch_bounds__(256) void scan_kernel(
    const float* __restrict__ IT, const float* __restrict__ FT,
    const float* __restrict__ ZT, const float* __restrict__ OT,
    const float* __restrict__ Ri, const float* __restrict__ Rf,
    const float* __restrict__ Rz, const float* __restrict__ Ro,
    const float* __restrict__ sng, const float* __restrict__ snb,
    float* __restrict__ Xr){
  int bh = blockIdx.x; int b = bh >> 2, h = bh & 3;
  int tid = threadIdx.x, w = tid >> 6, e = tid & 63;
  const float* Gp = (w == 0) ? IT : (w == 1) ? FT : (w == 2) ? ZT : OT;
  const float* Rg = ((w == 0) ? Ri : (w == 1) ? Rf : (w == 2) ? Rz : Ro) + h*4096;
  float rreg[64];
#pragma unroll
  for (int d = 0; d < 64; d++) rreg[d] = Rg[d*64 + e];
  __shared__ alignas(16) float hsh[64];
  __shared__ float gsh[4][64];
  float gw = 0.f, bw = 0.f, hS = 0.f, cS = 0.f, nS = 0.f, mS = 0.f;
  if (w == 0){ gw = sng[h*64 + e]; bw = snb[h*64 + e]; }
  if (tid < 64) hsh[tid] = 0.f;
  __syncthreads();
  size_t rowbase = ((size_t)b*256)*256 + h*64 + e;
  for (int s = 0; s < 256; s++){
    float pre = Gp[rowbase + (size_t)s*256];
#pragma unroll
    for (int d4 = 0; d4 < 16; d4++){
      float4 hv = *(const float4*)&hsh[d4*4];
      pre += hv.x*rreg[d4*4] + hv.y*rreg[d4*4+1] + hv.z*rreg[d4*4+2] + hv.w*rreg[d4*4+3];
    }
    gsh[w][e] = pre;
    __syncthreads();
    if (w == 0){
      float ip = gsh[0][e], fp = gsh[1][e];
      float zp = tanhf(gsh[2][e]);
      float op = 1.f / (1.f + __expf(-gsh[3][e]));
      float mn = fmaxf(fp + mS, ip);
      float ig = __expf(ip - mn);
      float fg = __expf(fp + mS - mn);
      cS = fg*cS + ig*zp;
      nS = fg*nS + ig;
      mS = mn;
      hS = op * cS / nS;
      float su = hS;
#pragma unroll
      for (int o = 32; o > 0; o >>= 1) su += __shfl_xor(su, o, 64);
      float mu = su * (1.f/64.f);
      float dv = hS - mu;
      float sq = dv*dv;
#pragma unroll
      for (int o = 32; o > 0; o >>= 1) sq += __shfl_xor(sq, o, 64);
      float nv = dv * rsqrtf(sq * (1.f/64.f) + 1e-6f) * gw + bw;
      hsh[e] = hS;
      Xr[rowbase + (size_t)s*256] += nv;
    }
    __syncthreads();
  }
}

// FFN activation: P = gelu_tanh(g) * u
__global__ __launch_bounds__(256) void ffn_act_kernel(const u16* __restrict__ GU,
                                                      u16* __restrict__ P){
  long long gid = (long long)blockIdx.x * 256 + threadIdx.x;   // T*352
  int j = (int)(gid % 352); long long t = gid / 352;
  float g = b2f(GU[(size_t)t*704 + j]);
  float u = b2f(GU[(size_t)t*704 + 352 + j]);
  float inner = 0.7978845608028654f * (g + 0.044715f*g*g*g);
  float gel = 0.5f * g * (1.f + tanhf(inner));
  P[(size_t)t*352 + j] = f2b(gel * u);
}

// output head: relu(last@W1+b1)@W2+b2, write in detected dtype
__global__ __launch_bounds__(64) void head_kernel(const float* __restrict__ X,
    const float* __restrict__ W1, const float* __restrict__ b1,
    const float* __restrict__ W2, const float* __restrict__ b2,
    void* out, const int* __restrict__ flag){
  int b = blockIdx.x, j = threadIdx.x;
  __shared__ float L[256];
  __shared__ float H1[64];
  for (int i = j; i < 256; i += 64) L[i] = X[((size_t)(b*256 + 255))*256 + i];
  __syncthreads();
  float acc = b1[j];
  for (int d = 0; d < 256; d++) acc += L[d] * W1[d*64 + j];
  H1[j] = fmaxf(acc, 0.f);
  __syncthreads();
  if (j < 3){
    float o = b2[j];
    for (int k2 = 0; k2 < 64; k2++) o += H1[k2] * W2[k2*3 + j];
    if (*flag) ((u16*)out)[b*3 + j] = f2b(o);
    else       ((float*)out)[b*3 + j] = o;
  }
}

// ----------------------------- launch --------------------------------------
extern "C" void kernel_launch(void* const* d_in, const int* in_sizes, int n_in,
                              void* d_out, int out_size, void* d_ws, size_t ws_size,
                              hipStream_t stream)
{
  if (n_in != IN_N) return;
  for (int i = 0; i < IN_N; i++) if ((long long)in_sizes[i] != IN_SIZES[i]) return;
  if (ws_size < (size_t)WS_END * 4) return;
  if (out_size != 384) return;

  float* ws = (float*)d_ws;
  float* cv = ws;
  auto cvp = [&](int i){ return cv + CVOFF.off[i]; };

  int*   flag = (int*)(ws + OFF_FLAG);
  float* IP   = ws + OFF_IP;
  float* FP   = ws + OFF_FP;
  float* Fb   = ws + OFF_F;
  float* Gb   = ws + OFF_G;
  float* Mb   = ws + OFF_M;
  float* X    = ws + OFF_X;
  u16*   XNb  = (u16*)(ws + OFF_XN);
  u16*   UPb  = (u16*)(ws + OFF_UP);
  u16*   Ab   = (u16*)(ws + OFF_A);
  u16*   Qb   = (u16*)(ws + OFF_Q);
  u16*   Kbb  = (u16*)(ws + OFF_K);
  u16*   Vb   = (u16*)(ws + OFF_V);
  u16*   WTb  = (u16*)(ws + OFF_WT);
  // overlays (lifetimes disjoint):
  float* CAT = ws + OFF_V;
  u16*   Yb  = Qb;
  u16*   ACb = Ab;
  float* ITf = ws + OFF_K;
  float* FTf = ws + OFF_V;
  float* ZTf = ws + OFF_Q;
  float* OTf = ws + OFF_UP;
  u16*   GUb = UPb;
  u16*   Pb  = Ab;

  auto wt = [&](int widx){ return WTb + WTO[widx]; };

  InPtrs ptrs;
  for (int i = 0; i < IN_N; i++) ptrs.p[i] = d_in[i];

  const int M = 32768;
  detect_kernel<<<1, 64, 0, stream>>>(d_in[7], flag);
  int cvblocks = (int)((CV_TOTAL + 255) / 256);
  convert_kernel<<<cvblocks, 256, 0, stream>>>(ptrs, cv, flag);
  wtrans_kernel<<<dim3(32, 16, 11), 256, 0, stream>>>(ptrs, WTb, flag);
  cat_kernel<<<5120, 256, 0, stream>>>(cvp(0), (const int*)d_in[1], (const int*)d_in[2],
                                       cvp(3), cvp(4), CAT);
  gemm_kernel<float, float><<<dim3(4, 512), 256, 0, stream>>>(CAT, 40, cvp(5), cvp(6),
      X, 256, nullptr, M, 256, 40);
  // ---- mLSTM block ----
  ln_kernel<<<M, 256, 0, stream>>>(X, cvp(7), cvp(8), XNb, 1e-5f);
  gemm_mfma<u16><<<dim3(8, 256), 256, 0, stream>>>(XNb, 256, wt(0), cvp(10),
      UPb, 1024, nullptr, 1024, 256);
  conv_silu_kernel<<<65536, 256, 0, stream>>>(UPb, 1024, 512, cvp(11), cvp(12), Ab);
  gemm_mfma<u16><<<dim3(4, 256), 256, 0, stream>>>(Ab, 512, wt(1), cvp(14),
      Qb, 512, nullptr, 512, 512);
  gemm_mfma<u16><<<dim3(4, 256), 256, 0, stream>>>(Ab, 512, wt(2), cvp(16),
      Kbb, 512, nullptr, 512, 512);
  gemm_mfma<u16><<<dim3(4, 256), 256, 0, stream>>>(UPb, 1024, wt(3), cvp(18),
      Vb, 512, nullptr, 512, 512);
  gates_kernel<<<M, 256, 0, stream>>>(Qb, Kbb, Vb, cvp(19), cvp(20), cvp(21), cvp(22), IP, FP);
  fscan_kernel<<<512, 256, 0, stream>>>(IP, FP, Fb, Gb, Mb);
  attn_kernel<<<dim3(4, 512), 256, 0, stream>>>(Qb, Kbb, Vb, Gb, Mb, Fb,
      Ab, UPb, cvp(24), cvp(25), cvp(23), Yb);
  gemm_mfma<float><<<dim3(2, 256), 256, 0, stream>>>(Yb, 512, wt(4), cvp(27),
      X, 256, X, 256, 512);
  // ---- sLSTM block ----
  ln_kernel<<<M, 256, 0, stream>>>(X, cvp(28), cvp(29), XNb, 1e-5f);
  conv_silu_kernel<<<32768, 256, 0, stream>>>(XNb, 256, 256, cvp(30), cvp(31), ACb);
  gemm_mfma<float><<<dim3(2, 256), 256, 0, stream>>>(ACb, 256, wt(5), cvp(33),
      ITf, 256, nullptr, 256, 256);
  gemm_mfma<float><<<dim3(2, 256), 256, 0, stream>>>(ACb, 256, wt(6), cvp(35),
      FTf, 256, nullptr, 256, 256);
  gemm_mfma<float><<<dim3(2, 256), 256, 0, stream>>>(XNb, 256, wt(7), cvp(37),
      ZTf, 256, nullptr, 256, 256);
  gemm_mfma<float><<<dim3(2, 256), 256, 0, stream>>>(XNb, 256, wt(8), cvp(39),
      OTf, 256, nullptr, 256, 256);
  scan_kernel<<<512, 256, 0, stream>>>(ITf, FTf, ZTf, OTf, cvp(40), cvp(41), cvp(42), cvp(43),
      cvp(44), cvp(45), X);
  // ---- FFN ----
  ln_kernel<<<M, 256, 0, stream>>>(X, cvp(46), cvp(47), XNb, 1e-5f);
  gemm_mfma<u16><<<dim3(6, 256), 256, 0, stream>>>(XNb, 256, wt(9), cvp(49),
      GUb, 704, nullptr, 704, 256);
  ffn_act_kernel<<<45056, 256, 0, stream>>>(GUb, Pb);
  gemm_mfma<float><<<dim3(2, 256), 256, 0, stream>>>(Pb, 352, wt(10), cvp(51),
      X, 256, X, 256, 352);
  // ---- head ----
  head_kernel<<<128, 64, 0, stream>>>(X, cvp(52), cvp(53), cvp(54), cvp(55), d_out, flag);
}

// Round 5
// 1304.195 us; speedup vs baseline: 2.6559x; 1.2621x over previous
//
#include <hip/hip_runtime.h>
#include <cstdint>
#include <cstddef>

// ---------------------------------------------------------------------------
// Model_xLSTM: B=128 S=256 NF=32 E=4 D=256 H=4 DI=512 DHM=128 DHS=64 K=4 FF=352
// Round 4: scan restructured (1 barrier/step, redundant per-wave state update,
// readlane h-broadcast, prefetched gate/X loads); ushort8/float4 vectorization
// of conv_silu / gates / ln / ffn_act. MFMA GEMM + attention unchanged (R3).
// ---------------------------------------------------------------------------

using u16 = unsigned short;
using u32 = unsigned int;

typedef __attribute__((ext_vector_type(8))) short short8;
typedef __attribute__((ext_vector_type(8))) unsigned short ushort8v;
typedef __attribute__((ext_vector_type(4))) float float4v;

#define DEVINL __device__ __forceinline__

DEVINL float b2f(u16 u){ u32 x = ((u32)u) << 16; return __builtin_bit_cast(float, x); }
DEVINL u16 f2b(float f){
  u32 x = __builtin_bit_cast(u32, f);
  u32 r = x + 0x7FFFu + ((x >> 16) & 1u);   // RTNE
  return (u16)(r >> 16);
}
DEVINL float ldval(float x){ return x; }
DEVINL float ldval(u16 x){ return b2f(x); }
DEVINL void stval(float* p, float v){ *p = v; }
DEVINL void stval(u16* p, float v){ *p = f2b(v); }

// ----------------------------- input table ---------------------------------
constexpr int IN_N = 56;
constexpr long long IN_SIZES[IN_N] = {
  1048576, 128, 128, 404, 28, 10240, 256, 256, 256,
  262144, 1024, 2048, 512,
  262144, 512, 262144, 512, 262144, 512,
  6144, 4, 6144, 4,
  512, 512, 512, 131072, 256,
  256, 256, 1024, 256,
  65536, 256, 65536, 256, 65536, 256, 65536, 256,
  16384, 16384, 16384, 16384,
  256, 256,
  256, 256, 180224, 704, 90112, 256,
  16384, 64, 192, 3 };

constexpr bool is_wt_input(int i){
  return i==9 || i==13 || i==15 || i==17 || i==26 || i==32 || i==34 || i==36
      || i==38 || i==48 || i==50;
}

struct CvOff { long long off[IN_N+1]; };
constexpr CvOff make_off(){
  CvOff o{};
  long long a = 0;
  for (int i = 0; i < IN_N; i++){
    o.off[i] = a;
    long long s = IN_SIZES[i];
    if (i == 1 || i == 2 || is_wt_input(i)) s = 0;
    a += s;
  }
  o.off[IN_N] = a;
  return o;
}
constexpr CvOff CVOFF = make_off();
constexpr long long CV_TOTAL = CVOFF.off[IN_N];

// transposed-weight table
constexpr int WT_NW = 11;
constexpr int WTB_IN[WT_NW] = {9, 13, 15, 17, 26, 32, 34, 36, 38, 48, 50};
constexpr int WTB_K[WT_NW]  = {256,512,512,512,512,256,256,256,256,256,352};
constexpr int WTB_N[WT_NW]  = {1024,512,512,512,256,256,256,256,256,704,256};
constexpr long long WTO[WT_NW+1] = {0, 262144, 524288, 786432, 1048576, 1179648,
  1245184, 1310720, 1376256, 1441792, 1622016, 1712128};
constexpr long long WT_ELEMS = WTO[WT_NW];

// ----------------------------- ws layout (float units) ---------------------
constexpr long long alignup(long long x){ return ((x + 255) / 256) * 256; }
constexpr long long TOK = 32768;            // B*S
constexpr long long OFF_FLAG = alignup(CV_TOTAL);
constexpr long long OFF_IP  = OFF_FLAG + 64;
constexpr long long OFF_FP  = OFF_IP  + 131072;
constexpr long long OFF_F   = OFF_FP  + 131072;
constexpr long long OFF_G   = OFF_F   + 131072;
constexpr long long OFF_M   = OFF_G   + 131072;
constexpr long long OFF_X   = OFF_M   + 131072;           // T x 256 fp32
constexpr long long OFF_XN  = OFF_X   + TOK*256;          // T x 256 bf16
constexpr long long OFF_UP  = OFF_XN  + TOK*128;          // T x 1024 bf16 (xm|zg)
constexpr long long OFF_A   = OFF_UP  + TOK*512;          // T x 512 bf16 (a / AC / P)
constexpr long long OFF_Q   = OFF_A   + TOK*256;          // T x 512 bf16 (q / Y / ZT fp32)
constexpr long long OFF_K   = OFF_Q   + TOK*256;          // T x 512 bf16 (k / IT fp32)
constexpr long long OFF_V   = OFF_K   + TOK*256;          // T x 512 bf16 (CAT / v / FT fp32)
constexpr long long OFF_WT  = OFF_V   + TOK*256;          // transposed bf16 weights
constexpr long long WS_END  = OFF_WT  + WT_ELEMS/2 + 256; // ~250 MiB

// ----------------------------- kernels -------------------------------------

__global__ void detect_kernel(const void* mlng, int* flag){
  if (threadIdx.x == 0){
    u32 u = *(const u32*)mlng;
    *flag = (u == 0x3F803F80u) ? 1 : 0;
  }
}

struct InPtrs { const void* p[IN_N]; };

__global__ __launch_bounds__(256) void convert_kernel(InPtrs ptrs, float* __restrict__ cv,
                                                      const int* __restrict__ flag){
  long long gid = (long long)blockIdx.x * 256 + threadIdx.x;
  if (gid >= CV_TOTAL) return;
  int seg = 0;
#pragma unroll
  for (int i = 1; i < IN_N; i++) seg += (gid >= CVOFF.off[i]) ? 1 : 0;
  long long local = gid - CVOFF.off[seg];
  float v;
  if (*flag) v = b2f(((const u16*)ptrs.p[seg])[local]);
  else       v = ((const float*)ptrs.p[seg])[local];
  cv[gid] = v;
}

// W[K][N] (fp32 or bf16 input) -> WT[N][K] bf16; 32x32 LDS tiles.
__global__ __launch_bounds__(256) void wtrans_kernel(InPtrs ptrs, u16* __restrict__ WTb,
                                                     const int* __restrict__ flag){
  int wz = blockIdx.z;
  int K = WTB_K[wz], N = WTB_N[wz];
  int n0 = blockIdx.x * 32, k0 = blockIdx.y * 32;
  if (n0 >= N || k0 >= K) return;
  const void* W = ptrs.p[WTB_IN[wz]];
  u16* WT = WTb + WTO[wz];
  __shared__ u16 tile[32][34];
  int tx = threadIdx.x & 31, ty = threadIdx.x >> 5;
  bool bf = (*flag != 0);
#pragma unroll
  for (int i = 0; i < 4; i++){
    size_t src = (size_t)(k0 + ty + i*8)*N + n0 + tx;
    tile[ty + i*8][tx] = bf ? ((const u16*)W)[src] : f2b(((const float*)W)[src]);
  }
  __syncthreads();
#pragma unroll
  for (int i = 0; i < 4; i++)
    WT[(size_t)(n0 + ty + i*8)*K + k0 + tx] = tile[tx][ty + i*8];
}

__global__ __launch_bounds__(256) void cat_kernel(const float* __restrict__ xs,
    const int* __restrict__ xe, const int* __restrict__ xp,
    const float* __restrict__ ee, const float* __restrict__ ep,
    float* __restrict__ CAT){
  int gid = blockIdx.x * 256 + threadIdx.x;   // T*40
  int c = gid % 40; int t = gid / 40; int b = t >> 8;
  float v;
  if (c < 32)      v = xs[(size_t)t*32 + c];
  else if (c < 36) v = ee[xe[b]*4 + (c - 32)];
  else             v = ep[xp[b]*4 + (c - 36)];
  CAT[(size_t)t*40 + c] = v;
}

// SIMT GEMM kept for W_in (K=40, fp32 in/out)
template<typename TA, typename TC>
__global__ __launch_bounds__(256) void gemm_kernel(
    const TA* __restrict__ A, int lda,
    const float* __restrict__ Wm, const float* __restrict__ bias,
    TC* __restrict__ Cc, int ldc, const float* __restrict__ resid,
    int M, int N, int K)
{
  __shared__ float As[16][68];
  __shared__ float Bs[16][68];
  const int bm = blockIdx.y * 64, bn = blockIdx.x * 64;
  const int tid = threadIdx.x, tx = tid & 15, ty = tid >> 4;
  float acc[4][4] = {};
  for (int k0 = 0; k0 < K; k0 += 16){
#pragma unroll
    for (int i = 0; i < 4; i++){
      int idx = tid + i*256;
      int m = idx >> 4, kq = idx & 15;
      As[kq][m] = (k0 + kq < K) ? ldval(A[(size_t)(bm + m)*lda + k0 + kq]) : 0.f;
      int kk = idx >> 6, n = idx & 63;
      Bs[kk][n] = (k0 + kk < K) ? Wm[(size_t)(k0 + kk)*N + bn + n] : 0.f;
    }
    __syncthreads();
#pragma unroll
    for (int kq = 0; kq < 16; kq++){
      float av[4], bv[4];
#pragma unroll
      for (int i = 0; i < 4; i++) av[i] = As[kq][ty*4 + i];
#pragma unroll
      for (int j = 0; j < 4; j++) bv[j] = Bs[kq][tx*4 + j];
#pragma unroll
      for (int i = 0; i < 4; i++)
#pragma unroll
        for (int j = 0; j < 4; j++) acc[i][j] += av[i]*bv[j];
    }
    __syncthreads();
  }
#pragma unroll
  for (int i = 0; i < 4; i++){
    int m = bm + ty*4 + i;
#pragma unroll
    for (int j = 0; j < 4; j++){
      int n = bn + tx*4 + j;
      float v = acc[i][j] + bias[n];
      if (resid) v += resid[(size_t)m*ldc + n];
      stval(&Cc[(size_t)m*ldc + n], v);
    }
  }
}

// MFMA GEMM: 128x128 macro tile, 4 waves 2x2, each 64x64 via 4x4 mfma_16x16x32.
template<typename TC>
__global__ __launch_bounds__(256) void gemm_mfma(
    const u16* __restrict__ A, int lda,
    const u16* __restrict__ WT,
    const float* __restrict__ bias,
    TC* __restrict__ Cc, int ldc, const float* __restrict__ resid,
    int N, int K)
{
  __shared__ alignas(16) u16 As[128*40];
  __shared__ alignas(16) u16 Bs[128*40];
  const int bm = blockIdx.y * 128, bn = blockIdx.x * 128;
  const int tid = threadIdx.x;
  const int w = tid >> 6, lane = tid & 63, lm = lane & 15, q = lane >> 4;
  const int wm = w >> 1, wn = w & 1;
  float4v acc[4][4] = {};
  for (int k0 = 0; k0 < K; k0 += 32){
    __syncthreads();
#pragma unroll
    for (int c = tid; c < 512; c += 256){
      int r = c >> 2, ch = c & 3;
      *(uint4*)&As[r*40 + ch*8] = *(const uint4*)&A[(size_t)(bm + r)*lda + k0 + ch*8];
      int n = bn + r;
      uint4 bv = {0u,0u,0u,0u};
      if (n < N) bv = *(const uint4*)&WT[(size_t)n*K + k0 + ch*8];
      *(uint4*)&Bs[r*40 + ch*8] = bv;
    }
    __syncthreads();
    short8 a[4], b[4];
#pragma unroll
    for (int i = 0; i < 4; i++)
      a[i] = *(const short8*)&As[(wm*64 + i*16 + lm)*40 + q*8];
#pragma unroll
    for (int j = 0; j < 4; j++)
      b[j] = *(const short8*)&Bs[(wn*64 + j*16 + lm)*40 + q*8];
#pragma unroll
    for (int i = 0; i < 4; i++)
#pragma unroll
      for (int j = 0; j < 4; j++)
        acc[i][j] = __builtin_amdgcn_mfma_f32_16x16x32_bf16(a[i], b[j], acc[i][j], 0, 0, 0);
  }
#pragma unroll
  for (int i = 0; i < 4; i++){
#pragma unroll
    for (int j = 0; j < 4; j++){
      int col = bn + wn*64 + j*16 + lm;
      if (col < N){
#pragma unroll
        for (int r = 0; r < 4; r++){
          int row = bm + wm*64 + i*16 + q*4 + r;
          float v = acc[i][j][r] + bias[col];
          if (resid) v += resid[(size_t)row*ldc + col];
          stval(&Cc[(size_t)row*ldc + col], v);
        }
      }
    }
  }
}

// LayerNorm: one wave per row, float4 loads, shuffle-only reductions.
__global__ __launch_bounds__(256) void ln_kernel(const float* __restrict__ Xin,
    const float* __restrict__ g, const float* __restrict__ b,
    u16* __restrict__ out, float eps){
  int t = blockIdx.x*4 + (threadIdx.x >> 6);
  int e = threadIdx.x & 63;
  float4 v = *(const float4*)&Xin[(size_t)t*256 + e*4];
  float su = v.x + v.y + v.z + v.w;
#pragma unroll
  for (int o = 32; o > 0; o >>= 1) su += __shfl_xor(su, o, 64);
  float mu = su * (1.f/256.f);
  float d0 = v.x - mu, d1 = v.y - mu, d2 = v.z - mu, d3 = v.w - mu;
  float sq = d0*d0 + d1*d1 + d2*d2 + d3*d3;
#pragma unroll
  for (int o = 32; o > 0; o >>= 1) sq += __shfl_xor(sq, o, 64);
  float rstd = rsqrtf(sq * (1.f/256.f) + eps);
  float4 gv = *(const float4*)&g[e*4];
  float4 bv = *(const float4*)&b[e*4];
  ushort4 o4;
  o4.x = f2b(d0*rstd*gv.x + bv.x);
  o4.y = f2b(d1*rstd*gv.y + bv.y);
  o4.z = f2b(d2*rstd*gv.z + bv.z);
  o4.w = f2b(d3*rstd*gv.w + bv.w);
  *(ushort4*)&out[(size_t)t*256 + e*4] = o4;
}

// depthwise causal conv (K=4) + silu, ushort8 vectorized (8 channels/thread)
__global__ __launch_bounds__(256) void conv_silu_kernel(const u16* __restrict__ Xc, int ldx, int C,
    const float* __restrict__ w, const float* __restrict__ bias, u16* __restrict__ Y){
  int nc = C >> 3;
  long long gid = (long long)blockIdx.x * 256 + threadIdx.x;   // T*nc
  int c8 = (int)(gid % nc) * 8; long long t = gid / nc;
  int s = (int)(t & 255);
  float acc[8];
#pragma unroll
  for (int i = 0; i < 8; i++) acc[i] = bias[c8 + i];
#pragma unroll
  for (int j = 0; j < 4; j++){
    int so = s - 3 + j;
    if (so >= 0){
      ushort8v xv = *(const ushort8v*)&Xc[(size_t)(t - 3 + j)*ldx + c8];
#pragma unroll
      for (int i = 0; i < 8; i++) acc[i] += b2f(xv[i]) * w[j*C + c8 + i];
    }
  }
  ushort8v o8;
#pragma unroll
  for (int i = 0; i < 8; i++) o8[i] = f2b(acc[i] / (1.f + __expf(-acc[i])));
  *(ushort8v*)&Y[(size_t)t*C + c8] = o8;
}

// ipre/fpre: gin=[q|k|v] (T x 1536) @ Wi/Wf (1536 x 4), ushort8 inner loads
__global__ __launch_bounds__(256) void gates_kernel(
    const u16* __restrict__ Q, const u16* __restrict__ Kb, const u16* __restrict__ V,
    const float* __restrict__ Wi, const float* __restrict__ bi,
    const float* __restrict__ Wf, const float* __restrict__ bf,
    float* __restrict__ IP, float* __restrict__ FP){
  int t = blockIdx.x; int tid = threadIdx.x;
  int o = tid & 7, seg = tid >> 3;
  int b = t >> 8, s = t & 255;
  int g = o & 3;
  const float* Wg = (o >= 4) ? Wf : Wi;
  float part = 0.f;
#pragma unroll
  for (int i = 0; i < 6; i++){
    int k8 = seg*48 + i*8;
    const u16* src; int off;
    if (k8 < 512){ src = Q; off = k8; }
    else if (k8 < 1024){ src = Kb; off = k8 - 512; }
    else { src = V; off = k8 - 1024; }
    ushort8v gv = *(const ushort8v*)&src[(size_t)t*512 + off];
#pragma unroll
    for (int j = 0; j < 8; j++) part += b2f(gv[j]) * Wg[(k8 + j)*4 + g];
  }
  __shared__ float red[256];
  red[tid] = part; __syncthreads();
  if (tid < 8){
    float tot = 0.f;
    for (int ss = 0; ss < 32; ss++) tot += red[ss*8 + tid];
    int gg = tid & 3;
    if (tid < 4) IP[(b*4 + gg)*256 + s] = tot + bi[gg];
    else         FP[(b*4 + gg)*256 + s] = tot + bf[gg];
  }
}

// per (b,h): F=cumsum(logsigmoid(fpre)); G=ipre-F; M=cummax(G)
__global__ __launch_bounds__(256) void fscan_kernel(const float* __restrict__ IP,
    const float* __restrict__ FP, float* __restrict__ Fo, float* __restrict__ Go,
    float* __restrict__ Mo){
  int bh = blockIdx.x; int s = threadIdx.x;
  int idx = bh*256 + s;
  __shared__ float buf[256];
  float fp = FP[idx];
  float lfg = fminf(fp, 0.f) - log1pf(expf(-fabsf(fp)));
  float v = lfg;
  buf[s] = v; __syncthreads();
  for (int off = 1; off < 256; off <<= 1){
    float tv = (s >= off) ? buf[s - off] : 0.f;
    __syncthreads();
    v += tv; buf[s] = v;
    __syncthreads();
  }
  float Fv = v;
  float g = IP[idx] - Fv;
  float mv = g;
  buf[s] = mv; __syncthreads();
  for (int off = 1; off < 256; off <<= 1){
    float tv = (s >= off) ? buf[s - off] : -3.0e38f;
    __syncthreads();
    mv = fmaxf(mv, tv); buf[s] = mv;
    __syncthreads();
  }
  Fo[idx] = Fv; Go[idx] = g; Mo[idx] = mv;
}

// Fused MFMA mLSTM attention (unchanged from R3).
__global__ __launch_bounds__(256) void attn_kernel(
    const u16* __restrict__ Q, const u16* __restrict__ Kb, const u16* __restrict__ V,
    const float* __restrict__ G, const float* __restrict__ Mx, const float* __restrict__ F,
    const u16* __restrict__ Ab, const u16* __restrict__ UPb,
    const float* __restrict__ ng, const float* __restrict__ nb,
    const float* __restrict__ skip, u16* __restrict__ Yb)
{
  int bh = blockIdx.y, b = bh >> 2, h = bh & 3;
  int tt = blockIdx.x, t0 = tt * 64;
  int tid = threadIdx.x;
  int w = tid >> 6, lane = tid & 63, lm = lane & 15, q = lane >> 4;
  int gbase = bh * 256;

  __shared__ alignas(16) u16 Qs[64*136];
  __shared__ alignas(16) u16 Ks[64*136];
  __shared__ alignas(16) u16 Vt[128*72];
  __shared__ alignas(16) u16 Ps[64*72];
  __shared__ float rs[64];

#pragma unroll
  for (int c = tid; c < 1024; c += 256){
    int r = c >> 4, ch = c & 15;
    *(uint4*)&Qs[r*136 + ch*8] =
      *(const uint4*)&Q[((size_t)(b*256 + t0 + r))*512 + h*128 + ch*8];
  }
  if (tid < 64) rs[tid] = 0.f;

  float mrow[4];
#pragma unroll
  for (int r = 0; r < 4; r++) mrow[r] = Mx[gbase + t0 + w*16 + q*4 + r];

  float4v acc2[8] = {};
  const float scale = 0.08838834764831845f;

  for (int ss = 0; ss <= tt; ss++){
    int s0 = ss * 64;
    __syncthreads();
#pragma unroll
    for (int c = tid; c < 1024; c += 256){
      int r = c >> 4, ch = c & 15;
      *(uint4*)&Ks[r*136 + ch*8] =
        *(const uint4*)&Kb[((size_t)(b*256 + s0 + r))*512 + h*128 + ch*8];
    }
#pragma unroll
    for (int c = tid; c < 1024; c += 256){
      int sl = c & 63, db = c >> 6;
      ushort8v v = *(const ushort8v*)&V[((size_t)(b*256 + s0 + sl))*512 + h*128 + db*8];
#pragma unroll
      for (int j = 0; j < 8; j++) Vt[(db*8 + j)*72 + sl] = v[j];
    }
    __syncthreads();
    float4v sacc[4] = {};
#pragma unroll
    for (int k0 = 0; k0 < 128; k0 += 32){
      short8 a = *(const short8*)&Qs[(w*16 + lm)*136 + k0 + q*8];
#pragma unroll
      for (int j = 0; j < 4; j++){
        short8 bb = *(const short8*)&Ks[(j*16 + lm)*136 + k0 + q*8];
        sacc[j] = __builtin_amdgcn_mfma_f32_16x16x32_bf16(a, bb, sacc[j], 0, 0, 0);
      }
    }
    float rp[4] = {0.f, 0.f, 0.f, 0.f};
#pragma unroll
    for (int j = 0; j < 4; j++){
      int scol = s0 + j*16 + lm;
      float gq = G[gbase + scol];
#pragma unroll
      for (int r = 0; r < 4; r++){
        int trow = t0 + w*16 + q*4 + r;
        float cval = (scol <= trow) ? sacc[j][r]*scale*__expf(gq - mrow[r]) : 0.f;
        Ps[(w*16 + q*4 + r)*72 + j*16 + lm] = f2b(cval);
        rp[r] += cval;
      }
    }
#pragma unroll
    for (int r = 0; r < 4; r++){
#pragma unroll
      for (int m = 1; m < 16; m <<= 1) rp[r] += __shfl_xor(rp[r], m, 16);
      if (lm == 0) rs[w*16 + q*4 + r] += rp[r];
    }
#pragma unroll
    for (int k0 = 0; k0 < 64; k0 += 32){
      short8 a = *(const short8*)&Ps[(w*16 + lm)*72 + k0 + q*8];
#pragma unroll
      for (int jd = 0; jd < 8; jd++){
        short8 bb = *(const short8*)&Vt[(jd*16 + lm)*72 + k0 + q*8];
        acc2[jd] = __builtin_amdgcn_mfma_f32_16x16x32_bf16(a, bb, acc2[jd], 0, 0, 0);
      }
    }
  }
  __syncthreads();
#pragma unroll
  for (int r = 0; r < 4; r++){
    int rl = w*16 + q*4 + r;
    int t = t0 + rl;
    float Fv = F[gbase + t];
    float nrm = fmaxf(fabsf(rs[rl]), __expf(-(Fv + mrow[r])));
    float inv = 1.f / nrm;
    float vv[8];
    float su = 0.f;
#pragma unroll
    for (int jd = 0; jd < 8; jd++){ vv[jd] = acc2[jd][r]*inv; su += vv[jd]; }
#pragma unroll
    for (int m = 1; m < 16; m <<= 1) su += __shfl_xor(su, m, 16);
    float mu = su * (1.f/128.f);
    float sq = 0.f;
#pragma unroll
    for (int jd = 0; jd < 8; jd++){ vv[jd] -= mu; sq += vv[jd]*vv[jd]; }
#pragma unroll
    for (int m = 1; m < 16; m <<= 1) sq += __shfl_xor(sq, m, 16);
    float rstd = rsqrtf(sq * (1.f/128.f) + 1e-6f);
#pragma unroll
    for (int jd = 0; jd < 8; jd++){
      int c = h*128 + jd*16 + lm;
      float hv = vv[jd]*rstd*ng[c] + nb[c];
      float av = b2f(Ab[(size_t)t*512 + c]);
      float zg = b2f(UPb[(size_t)t*1024 + 512 + c]);
      float sz = zg / (1.f + __expf(-zg));
      Yb[(size_t)t*512 + c] = f2b((hv + skip[c]*av)*sz);
    }
  }
}

// sLSTM recurrence: block=(b,h), 4 waves (one per gate), redundant per-wave
// state update, readlane h-broadcast, 1 barrier/step, prefetched loads.
__global__ __launch_bounds__(256) void scan_kernel(
    const float* __restrict__ IT, const float* __restrict__ FT,
    const float* __restrict__ ZT, const float* __restrict__ OT,
    const float* __restrict__ Ri, const float* __restrict__ Rf,
    const float* __restrict__ Rz, const float* __restrict__ Ro,
    const float* __restrict__ sng, const float* __restrict__ snb,
    float* __restrict__ Xr){
  int bh = blockIdx.x; int b = bh >> 2, h = bh & 3;
  int tid = threadIdx.x, w = tid >> 6, e = tid & 63;
  const float* Gp = (w == 0) ? IT : (w == 1) ? FT : (w == 2) ? ZT : OT;
  const float* Rg = ((w == 0) ? Ri : (w == 1) ? Rf : (w == 2) ? Rz : Ro) + h*4096;
  float rreg[64];
#pragma unroll
  for (int d = 0; d < 64; d++) rreg[d] = Rg[d*64 + e];
  __shared__ float gsh[2][4][64];
  float gw = 0.f, bw = 0.f;
  if (w == 0){ gw = sng[h*64 + e]; bw = snb[h*64 + e]; }
  float hS = 0.f, cS = 0.f, nS = 0.f, mS = 0.f;
  size_t rowbase = ((size_t)b*256)*256 + h*64 + e;
  float gcur = Gp[rowbase];
  float xcur = (w == 0) ? Xr[rowbase] : 0.f;
  for (int s = 0; s < 256; s++){
    float gnext = 0.f, xnext = 0.f;
    if (s < 255){
      gnext = Gp[rowbase + (size_t)(s+1)*256];
      if (w == 0) xnext = Xr[rowbase + (size_t)(s+1)*256];
    }
    float pre = gcur;
#pragma unroll
    for (int d = 0; d < 64; d++){
      float hd = __builtin_bit_cast(float,
          __builtin_amdgcn_readlane(__builtin_bit_cast(int, hS), d));
      pre += hd * rreg[d];
    }
    gsh[s & 1][w][e] = pre;
    __syncthreads();
    float ip = gsh[s & 1][0][e];
    float fp = gsh[s & 1][1][e];
    float zp = tanhf(gsh[s & 1][2][e]);
    float op = 1.f / (1.f + __expf(-gsh[s & 1][3][e]));
    float mn = fmaxf(fp + mS, ip);
    float ig = __expf(ip - mn);
    float fg = __expf(fp + mS - mn);
    cS = fg*cS + ig*zp;
    nS = fg*nS + ig;
    mS = mn;
    hS = op * cS / nS;
    if (w == 0){
      float su = hS, sq = hS*hS;
#pragma unroll
      for (int o = 32; o > 0; o >>= 1){
        su += __shfl_xor(su, o, 64);
        sq += __shfl_xor(sq, o, 64);
      }
      float mu = su * (1.f/64.f);
      float var = fmaxf(sq * (1.f/64.f) - mu*mu, 0.f);
      float nv = (hS - mu) * rsqrtf(var + 1e-6f) * gw + bw;
      Xr[rowbase + (size_t)s*256] = xcur + nv;
      xcur = xnext;
    }
    gcur = gnext;
  }
}

// FFN activation: P = gelu_tanh(g) * u, ushort8 vectorized
__global__ __launch_bounds__(256) void ffn_act_kernel(const u16* __restrict__ GU,
                                                      u16* __restrict__ P){
  long long gid = (long long)blockIdx.x * 256 + threadIdx.x;   // T*44
  int j8 = (int)(gid % 44) * 8; long long t = gid / 44;
  ushort8v gv = *(const ushort8v*)&GU[(size_t)t*704 + j8];
  ushort8v uv = *(const ushort8v*)&GU[(size_t)t*704 + 352 + j8];
  ushort8v o8;
#pragma unroll
  for (int i = 0; i < 8; i++){
    float g = b2f(gv[i]);
    float u = b2f(uv[i]);
    float inner = 0.7978845608028654f * (g + 0.044715f*g*g*g);
    float gel = 0.5f * g * (1.f + tanhf(inner));
    o8[i] = f2b(gel * u);
  }
  *(ushort8v*)&P[(size_t)t*352 + j8] = o8;
}

// output head: relu(last@W1+b1)@W2+b2, write in detected dtype
__global__ __launch_bounds__(64) void head_kernel(const float* __restrict__ X,
    const float* __restrict__ W1, const float* __restrict__ b1,
    const float* __restrict__ W2, const float* __restrict__ b2,
    void* out, const int* __restrict__ flag){
  int b = blockIdx.x, j = threadIdx.x;
  __shared__ float L[256];
  __shared__ float H1[64];
  for (int i = j; i < 256; i += 64) L[i] = X[((size_t)(b*256 + 255))*256 + i];
  __syncthreads();
  float acc = b1[j];
  for (int d = 0; d < 256; d++) acc += L[d] * W1[d*64 + j];
  H1[j] = fmaxf(acc, 0.f);
  __syncthreads();
  if (j < 3){
    float o = b2[j];
    for (int k2 = 0; k2 < 64; k2++) o += H1[k2] * W2[k2*3 + j];
    if (*flag) ((u16*)out)[b*3 + j] = f2b(o);
    else       ((float*)out)[b*3 + j] = o;
  }
}

// ----------------------------- launch --------------------------------------
extern "C" void kernel_launch(void* const* d_in, const int* in_sizes, int n_in,
                              void* d_out, int out_size, void* d_ws, size_t ws_size,
                              hipStream_t stream)
{
  if (n_in != IN_N) return;
  for (int i = 0; i < IN_N; i++) if ((long long)in_sizes[i] != IN_SIZES[i]) return;
  if (ws_size < (size_t)WS_END * 4) return;
  if (out_size != 384) return;

  float* ws = (float*)d_ws;
  float* cv = ws;
  auto cvp = [&](int i){ return cv + CVOFF.off[i]; };

  int*   flag = (int*)(ws + OFF_FLAG);
  float* IP   = ws + OFF_IP;
  float* FP   = ws + OFF_FP;
  float* Fb   = ws + OFF_F;
  float* Gb   = ws + OFF_G;
  float* Mb   = ws + OFF_M;
  float* X    = ws + OFF_X;
  u16*   XNb  = (u16*)(ws + OFF_XN);
  u16*   UPb  = (u16*)(ws + OFF_UP);
  u16*   Ab   = (u16*)(ws + OFF_A);
  u16*   Qb   = (u16*)(ws + OFF_Q);
  u16*   Kbb  = (u16*)(ws + OFF_K);
  u16*   Vb   = (u16*)(ws + OFF_V);
  u16*   WTb  = (u16*)(ws + OFF_WT);
  // overlays (lifetimes disjoint):
  float* CAT = ws + OFF_V;
  u16*   Yb  = Qb;
  u16*   ACb = Ab;
  float* ITf = ws + OFF_K;
  float* FTf = ws + OFF_V;
  float* ZTf = ws + OFF_Q;
  float* OTf = ws + OFF_UP;
  u16*   GUb = UPb;
  u16*   Pb  = Ab;

  auto wt = [&](int widx){ return WTb + WTO[widx]; };

  InPtrs ptrs;
  for (int i = 0; i < IN_N; i++) ptrs.p[i] = d_in[i];

  const int M = 32768;
  detect_kernel<<<1, 64, 0, stream>>>(d_in[7], flag);
  int cvblocks = (int)((CV_TOTAL + 255) / 256);
  convert_kernel<<<cvblocks, 256, 0, stream>>>(ptrs, cv, flag);
  wtrans_kernel<<<dim3(32, 16, 11), 256, 0, stream>>>(ptrs, WTb, flag);
  cat_kernel<<<5120, 256, 0, stream>>>(cvp(0), (const int*)d_in[1], (const int*)d_in[2],
                                       cvp(3), cvp(4), CAT);
  gemm_kernel<float, float><<<dim3(4, 512), 256, 0, stream>>>(CAT, 40, cvp(5), cvp(6),
      X, 256, nullptr, M, 256, 40);
  // ---- mLSTM block ----
  ln_kernel<<<8192, 256, 0, stream>>>(X, cvp(7), cvp(8), XNb, 1e-5f);
  gemm_mfma<u16><<<dim3(8, 256), 256, 0, stream>>>(XNb, 256, wt(0), cvp(10),
      UPb, 1024, nullptr, 1024, 256);
  conv_silu_kernel<<<8192, 256, 0, stream>>>(UPb, 1024, 512, cvp(11), cvp(12), Ab);
  gemm_mfma<u16><<<dim3(4, 256), 256, 0, stream>>>(Ab, 512, wt(1), cvp(14),
      Qb, 512, nullptr, 512, 512);
  gemm_mfma<u16><<<dim3(4, 256), 256, 0, stream>>>(Ab, 512, wt(2), cvp(16),
      Kbb, 512, nullptr, 512, 512);
  gemm_mfma<u16><<<dim3(4, 256), 256, 0, stream>>>(UPb, 1024, wt(3), cvp(18),
      Vb, 512, nullptr, 512, 512);
  gates_kernel<<<M, 256, 0, stream>>>(Qb, Kbb, Vb, cvp(19), cvp(20), cvp(21), cvp(22), IP, FP);
  fscan_kernel<<<512, 256, 0, stream>>>(IP, FP, Fb, Gb, Mb);
  attn_kernel<<<dim3(4, 512), 256, 0, stream>>>(Qb, Kbb, Vb, Gb, Mb, Fb,
      Ab, UPb, cvp(24), cvp(25), cvp(23), Yb);
  gemm_mfma<float><<<dim3(2, 256), 256, 0, stream>>>(Yb, 512, wt(4), cvp(27),
      X, 256, X, 256, 512);
  // ---- sLSTM block ----
  ln_kernel<<<8192, 256, 0, stream>>>(X, cvp(28), cvp(29), XNb, 1e-5f);
  conv_silu_kernel<<<4096, 256, 0, stream>>>(XNb, 256, 256, cvp(30), cvp(31), ACb);
  gemm_mfma<float><<<dim3(2, 256), 256, 0, stream>>>(ACb, 256, wt(5), cvp(33),
      ITf, 256, nullptr, 256, 256);
  gemm_mfma<float><<<dim3(2, 256), 256, 0, stream>>>(ACb, 256, wt(6), cvp(35),
      FTf, 256, nullptr, 256, 256);
  gemm_mfma<float><<<dim3(2, 256), 256, 0, stream>>>(XNb, 256, wt(7), cvp(37),
      ZTf, 256, nullptr, 256, 256);
  gemm_mfma<float><<<dim3(2, 256), 256, 0, stream>>>(XNb, 256, wt(8), cvp(39),
      OTf, 256, nullptr, 256, 256);
  scan_kernel<<<512, 256, 0, stream>>>(ITf, FTf, ZTf, OTf, cvp(40), cvp(41), cvp(42), cvp(43),
      cvp(44), cvp(45), X);
  // ---- FFN ----
  ln_kernel<<<8192, 256, 0, stream>>>(X, cvp(46), cvp(47), XNb, 1e-5f);
  gemm_mfma<u16><<<dim3(6, 256), 256, 0, stream>>>(XNb, 256, wt(9), cvp(49),
      GUb, 704, nullptr, 704, 256);
  ffn_act_kernel<<<5632, 256, 0, stream>>>(GUb, Pb);
  gemm_mfma<float><<<dim3(2, 256), 256, 0, stream>>>(Pb, 352, wt(10), cvp(51),
      X, 256, X, 256, 352);
  // ---- head ----
  head_kernel<<<128, 64, 0, stream>>>(X, cvp(52), cvp(53), cvp(54), cvp(55), d_out, flag);
}

// Round 6
// 1231.583 us; speedup vs baseline: 2.8125x; 1.0590x over previous
//
#include <hip/hip_runtime.h>
#include <cstdint>
#include <cstddef>

// ---------------------------------------------------------------------------
// Model_xLSTM: B=128 S=256 NF=32 E=4 D=256 H=4 DI=512 DHM=128 DHS=64 K=4 FF=352
// Round 5: scan -> single-wave per (b,h), R in 256 VGPRs, no barriers/LDS,
// 8-way split accumulator chains, 1-step load prefetch. Rest frozen (R4).
// ---------------------------------------------------------------------------

using u16 = unsigned short;
using u32 = unsigned int;

typedef __attribute__((ext_vector_type(8))) short short8;
typedef __attribute__((ext_vector_type(8))) unsigned short ushort8v;
typedef __attribute__((ext_vector_type(4))) float float4v;

#define DEVINL __device__ __forceinline__

DEVINL float b2f(u16 u){ u32 x = ((u32)u) << 16; return __builtin_bit_cast(float, x); }
DEVINL u16 f2b(float f){
  u32 x = __builtin_bit_cast(u32, f);
  u32 r = x + 0x7FFFu + ((x >> 16) & 1u);   // RTNE
  return (u16)(r >> 16);
}
DEVINL float ldval(float x){ return x; }
DEVINL float ldval(u16 x){ return b2f(x); }
DEVINL void stval(float* p, float v){ *p = v; }
DEVINL void stval(u16* p, float v){ *p = f2b(v); }

// ----------------------------- input table ---------------------------------
constexpr int IN_N = 56;
constexpr long long IN_SIZES[IN_N] = {
  1048576, 128, 128, 404, 28, 10240, 256, 256, 256,
  262144, 1024, 2048, 512,
  262144, 512, 262144, 512, 262144, 512,
  6144, 4, 6144, 4,
  512, 512, 512, 131072, 256,
  256, 256, 1024, 256,
  65536, 256, 65536, 256, 65536, 256, 65536, 256,
  16384, 16384, 16384, 16384,
  256, 256,
  256, 256, 180224, 704, 90112, 256,
  16384, 64, 192, 3 };

constexpr bool is_wt_input(int i){
  return i==9 || i==13 || i==15 || i==17 || i==26 || i==32 || i==34 || i==36
      || i==38 || i==48 || i==50;
}

struct CvOff { long long off[IN_N+1]; };
constexpr CvOff make_off(){
  CvOff o{};
  long long a = 0;
  for (int i = 0; i < IN_N; i++){
    o.off[i] = a;
    long long s = IN_SIZES[i];
    if (i == 1 || i == 2 || is_wt_input(i)) s = 0;
    a += s;
  }
  o.off[IN_N] = a;
  return o;
}
constexpr CvOff CVOFF = make_off();
constexpr long long CV_TOTAL = CVOFF.off[IN_N];

// transposed-weight table
constexpr int WT_NW = 11;
constexpr int WTB_IN[WT_NW] = {9, 13, 15, 17, 26, 32, 34, 36, 38, 48, 50};
constexpr int WTB_K[WT_NW]  = {256,512,512,512,512,256,256,256,256,256,352};
constexpr int WTB_N[WT_NW]  = {1024,512,512,512,256,256,256,256,256,704,256};
constexpr long long WTO[WT_NW+1] = {0, 262144, 524288, 786432, 1048576, 1179648,
  1245184, 1310720, 1376256, 1441792, 1622016, 1712128};
constexpr long long WT_ELEMS = WTO[WT_NW];

// ----------------------------- ws layout (float units) ---------------------
constexpr long long alignup(long long x){ return ((x + 255) / 256) * 256; }
constexpr long long TOK = 32768;            // B*S
constexpr long long OFF_FLAG = alignup(CV_TOTAL);
constexpr long long OFF_IP  = OFF_FLAG + 64;
constexpr long long OFF_FP  = OFF_IP  + 131072;
constexpr long long OFF_F   = OFF_FP  + 131072;
constexpr long long OFF_G   = OFF_F   + 131072;
constexpr long long OFF_M   = OFF_G   + 131072;
constexpr long long OFF_X   = OFF_M   + 131072;           // T x 256 fp32
constexpr long long OFF_XN  = OFF_X   + TOK*256;          // T x 256 bf16
constexpr long long OFF_UP  = OFF_XN  + TOK*128;          // T x 1024 bf16 (xm|zg)
constexpr long long OFF_A   = OFF_UP  + TOK*512;          // T x 512 bf16 (a / AC / P)
constexpr long long OFF_Q   = OFF_A   + TOK*256;          // T x 512 bf16 (q / Y / ZT fp32)
constexpr long long OFF_K   = OFF_Q   + TOK*256;          // T x 512 bf16 (k / IT fp32)
constexpr long long OFF_V   = OFF_K   + TOK*256;          // T x 512 bf16 (CAT / v / FT fp32)
constexpr long long OFF_WT  = OFF_V   + TOK*256;          // transposed bf16 weights
constexpr long long WS_END  = OFF_WT  + WT_ELEMS/2 + 256; // ~250 MiB

// ----------------------------- kernels -------------------------------------

__global__ void detect_kernel(const void* mlng, int* flag){
  if (threadIdx.x == 0){
    u32 u = *(const u32*)mlng;
    *flag = (u == 0x3F803F80u) ? 1 : 0;
  }
}

struct InPtrs { const void* p[IN_N]; };

__global__ __launch_bounds__(256) void convert_kernel(InPtrs ptrs, float* __restrict__ cv,
                                                      const int* __restrict__ flag){
  long long gid = (long long)blockIdx.x * 256 + threadIdx.x;
  if (gid >= CV_TOTAL) return;
  int seg = 0;
#pragma unroll
  for (int i = 1; i < IN_N; i++) seg += (gid >= CVOFF.off[i]) ? 1 : 0;
  long long local = gid - CVOFF.off[seg];
  float v;
  if (*flag) v = b2f(((const u16*)ptrs.p[seg])[local]);
  else       v = ((const float*)ptrs.p[seg])[local];
  cv[gid] = v;
}

// W[K][N] (fp32 or bf16 input) -> WT[N][K] bf16; 32x32 LDS tiles.
__global__ __launch_bounds__(256) void wtrans_kernel(InPtrs ptrs, u16* __restrict__ WTb,
                                                     const int* __restrict__ flag){
  int wz = blockIdx.z;
  int K = WTB_K[wz], N = WTB_N[wz];
  int n0 = blockIdx.x * 32, k0 = blockIdx.y * 32;
  if (n0 >= N || k0 >= K) return;
  const void* W = ptrs.p[WTB_IN[wz]];
  u16* WT = WTb + WTO[wz];
  __shared__ u16 tile[32][34];
  int tx = threadIdx.x & 31, ty = threadIdx.x >> 5;
  bool bf = (*flag != 0);
#pragma unroll
  for (int i = 0; i < 4; i++){
    size_t src = (size_t)(k0 + ty + i*8)*N + n0 + tx;
    tile[ty + i*8][tx] = bf ? ((const u16*)W)[src] : f2b(((const float*)W)[src]);
  }
  __syncthreads();
#pragma unroll
  for (int i = 0; i < 4; i++)
    WT[(size_t)(n0 + ty + i*8)*K + k0 + tx] = tile[tx][ty + i*8];
}

__global__ __launch_bounds__(256) void cat_kernel(const float* __restrict__ xs,
    const int* __restrict__ xe, const int* __restrict__ xp,
    const float* __restrict__ ee, const float* __restrict__ ep,
    float* __restrict__ CAT){
  int gid = blockIdx.x * 256 + threadIdx.x;   // T*40
  int c = gid % 40; int t = gid / 40; int b = t >> 8;
  float v;
  if (c < 32)      v = xs[(size_t)t*32 + c];
  else if (c < 36) v = ee[xe[b]*4 + (c - 32)];
  else             v = ep[xp[b]*4 + (c - 36)];
  CAT[(size_t)t*40 + c] = v;
}

// SIMT GEMM kept for W_in (K=40, fp32 in/out)
template<typename TA, typename TC>
__global__ __launch_bounds__(256) void gemm_kernel(
    const TA* __restrict__ A, int lda,
    const float* __restrict__ Wm, const float* __restrict__ bias,
    TC* __restrict__ Cc, int ldc, const float* __restrict__ resid,
    int M, int N, int K)
{
  __shared__ float As[16][68];
  __shared__ float Bs[16][68];
  const int bm = blockIdx.y * 64, bn = blockIdx.x * 64;
  const int tid = threadIdx.x, tx = tid & 15, ty = tid >> 4;
  float acc[4][4] = {};
  for (int k0 = 0; k0 < K; k0 += 16){
#pragma unroll
    for (int i = 0; i < 4; i++){
      int idx = tid + i*256;
      int m = idx >> 4, kq = idx & 15;
      As[kq][m] = (k0 + kq < K) ? ldval(A[(size_t)(bm + m)*lda + k0 + kq]) : 0.f;
      int kk = idx >> 6, n = idx & 63;
      Bs[kk][n] = (k0 + kk < K) ? Wm[(size_t)(k0 + kk)*N + bn + n] : 0.f;
    }
    __syncthreads();
#pragma unroll
    for (int kq = 0; kq < 16; kq++){
      float av[4], bv[4];
#pragma unroll
      for (int i = 0; i < 4; i++) av[i] = As[kq][ty*4 + i];
#pragma unroll
      for (int j = 0; j < 4; j++) bv[j] = Bs[kq][tx*4 + j];
#pragma unroll
      for (int i = 0; i < 4; i++)
#pragma unroll
        for (int j = 0; j < 4; j++) acc[i][j] += av[i]*bv[j];
    }
    __syncthreads();
  }
#pragma unroll
  for (int i = 0; i < 4; i++){
    int m = bm + ty*4 + i;
#pragma unroll
    for (int j = 0; j < 4; j++){
      int n = bn + tx*4 + j;
      float v = acc[i][j] + bias[n];
      if (resid) v += resid[(size_t)m*ldc + n];
      stval(&Cc[(size_t)m*ldc + n], v);
    }
  }
}

// MFMA GEMM: 128x128 macro tile, 4 waves 2x2, each 64x64 via 4x4 mfma_16x16x32.
template<typename TC>
__global__ __launch_bounds__(256) void gemm_mfma(
    const u16* __restrict__ A, int lda,
    const u16* __restrict__ WT,
    const float* __restrict__ bias,
    TC* __restrict__ Cc, int ldc, const float* __restrict__ resid,
    int N, int K)
{
  __shared__ alignas(16) u16 As[128*40];
  __shared__ alignas(16) u16 Bs[128*40];
  const int bm = blockIdx.y * 128, bn = blockIdx.x * 128;
  const int tid = threadIdx.x;
  const int w = tid >> 6, lane = tid & 63, lm = lane & 15, q = lane >> 4;
  const int wm = w >> 1, wn = w & 1;
  float4v acc[4][4] = {};
  for (int k0 = 0; k0 < K; k0 += 32){
    __syncthreads();
#pragma unroll
    for (int c = tid; c < 512; c += 256){
      int r = c >> 2, ch = c & 3;
      *(uint4*)&As[r*40 + ch*8] = *(const uint4*)&A[(size_t)(bm + r)*lda + k0 + ch*8];
      int n = bn + r;
      uint4 bv = {0u,0u,0u,0u};
      if (n < N) bv = *(const uint4*)&WT[(size_t)n*K + k0 + ch*8];
      *(uint4*)&Bs[r*40 + ch*8] = bv;
    }
    __syncthreads();
    short8 a[4], b[4];
#pragma unroll
    for (int i = 0; i < 4; i++)
      a[i] = *(const short8*)&As[(wm*64 + i*16 + lm)*40 + q*8];
#pragma unroll
    for (int j = 0; j < 4; j++)
      b[j] = *(const short8*)&Bs[(wn*64 + j*16 + lm)*40 + q*8];
#pragma unroll
    for (int i = 0; i < 4; i++)
#pragma unroll
      for (int j = 0; j < 4; j++)
        acc[i][j] = __builtin_amdgcn_mfma_f32_16x16x32_bf16(a[i], b[j], acc[i][j], 0, 0, 0);
  }
#pragma unroll
  for (int i = 0; i < 4; i++){
#pragma unroll
    for (int j = 0; j < 4; j++){
      int col = bn + wn*64 + j*16 + lm;
      if (col < N){
#pragma unroll
        for (int r = 0; r < 4; r++){
          int row = bm + wm*64 + i*16 + q*4 + r;
          float v = acc[i][j][r] + bias[col];
          if (resid) v += resid[(size_t)row*ldc + col];
          stval(&Cc[(size_t)row*ldc + col], v);
        }
      }
    }
  }
}

// LayerNorm: one wave per row, float4 loads, shuffle-only reductions.
__global__ __launch_bounds__(256) void ln_kernel(const float* __restrict__ Xin,
    const float* __restrict__ g, const float* __restrict__ b,
    u16* __restrict__ out, float eps){
  int t = blockIdx.x*4 + (threadIdx.x >> 6);
  int e = threadIdx.x & 63;
  float4 v = *(const float4*)&Xin[(size_t)t*256 + e*4];
  float su = v.x + v.y + v.z + v.w;
#pragma unroll
  for (int o = 32; o > 0; o >>= 1) su += __shfl_xor(su, o, 64);
  float mu = su * (1.f/256.f);
  float d0 = v.x - mu, d1 = v.y - mu, d2 = v.z - mu, d3 = v.w - mu;
  float sq = d0*d0 + d1*d1 + d2*d2 + d3*d3;
#pragma unroll
  for (int o = 32; o > 0; o >>= 1) sq += __shfl_xor(sq, o, 64);
  float rstd = rsqrtf(sq * (1.f/256.f) + eps);
  float4 gv = *(const float4*)&g[e*4];
  float4 bv = *(const float4*)&b[e*4];
  ushort4 o4;
  o4.x = f2b(d0*rstd*gv.x + bv.x);
  o4.y = f2b(d1*rstd*gv.y + bv.y);
  o4.z = f2b(d2*rstd*gv.z + bv.z);
  o4.w = f2b(d3*rstd*gv.w + bv.w);
  *(ushort4*)&out[(size_t)t*256 + e*4] = o4;
}

// depthwise causal conv (K=4) + silu, ushort8 vectorized (8 channels/thread)
__global__ __launch_bounds__(256) void conv_silu_kernel(const u16* __restrict__ Xc, int ldx, int C,
    const float* __restrict__ w, const float* __restrict__ bias, u16* __restrict__ Y){
  int nc = C >> 3;
  long long gid = (long long)blockIdx.x * 256 + threadIdx.x;   // T*nc
  int c8 = (int)(gid % nc) * 8; long long t = gid / nc;
  int s = (int)(t & 255);
  float acc[8];
#pragma unroll
  for (int i = 0; i < 8; i++) acc[i] = bias[c8 + i];
#pragma unroll
  for (int j = 0; j < 4; j++){
    int so = s - 3 + j;
    if (so >= 0){
      ushort8v xv = *(const ushort8v*)&Xc[(size_t)(t - 3 + j)*ldx + c8];
#pragma unroll
      for (int i = 0; i < 8; i++) acc[i] += b2f(xv[i]) * w[j*C + c8 + i];
    }
  }
  ushort8v o8;
#pragma unroll
  for (int i = 0; i < 8; i++) o8[i] = f2b(acc[i] / (1.f + __expf(-acc[i])));
  *(ushort8v*)&Y[(size_t)t*C + c8] = o8;
}

// ipre/fpre: gin=[q|k|v] (T x 1536) @ Wi/Wf (1536 x 4), ushort8 inner loads
__global__ __launch_bounds__(256) void gates_kernel(
    const u16* __restrict__ Q, const u16* __restrict__ Kb, const u16* __restrict__ V,
    const float* __restrict__ Wi, const float* __restrict__ bi,
    const float* __restrict__ Wf, const float* __restrict__ bf,
    float* __restrict__ IP, float* __restrict__ FP){
  int t = blockIdx.x; int tid = threadIdx.x;
  int o = tid & 7, seg = tid >> 3;
  int b = t >> 8, s = t & 255;
  int g = o & 3;
  const float* Wg = (o >= 4) ? Wf : Wi;
  float part = 0.f;
#pragma unroll
  for (int i = 0; i < 6; i++){
    int k8 = seg*48 + i*8;
    const u16* src; int off;
    if (k8 < 512){ src = Q; off = k8; }
    else if (k8 < 1024){ src = Kb; off = k8 - 512; }
    else { src = V; off = k8 - 1024; }
    ushort8v gv = *(const ushort8v*)&src[(size_t)t*512 + off];
#pragma unroll
    for (int j = 0; j < 8; j++) part += b2f(gv[j]) * Wg[(k8 + j)*4 + g];
  }
  __shared__ float red[256];
  red[tid] = part; __syncthreads();
  if (tid < 8){
    float tot = 0.f;
    for (int ss = 0; ss < 32; ss++) tot += red[ss*8 + tid];
    int gg = tid & 3;
    if (tid < 4) IP[(b*4 + gg)*256 + s] = tot + bi[gg];
    else         FP[(b*4 + gg)*256 + s] = tot + bf[gg];
  }
}

// per (b,h): F=cumsum(logsigmoid(fpre)); G=ipre-F; M=cummax(G)
__global__ __launch_bounds__(256) void fscan_kernel(const float* __restrict__ IP,
    const float* __restrict__ FP, float* __restrict__ Fo, float* __restrict__ Go,
    float* __restrict__ Mo){
  int bh = blockIdx.x; int s = threadIdx.x;
  int idx = bh*256 + s;
  __shared__ float buf[256];
  float fp = FP[idx];
  float lfg = fminf(fp, 0.f) - log1pf(expf(-fabsf(fp)));
  float v = lfg;
  buf[s] = v; __syncthreads();
  for (int off = 1; off < 256; off <<= 1){
    float tv = (s >= off) ? buf[s - off] : 0.f;
    __syncthreads();
    v += tv; buf[s] = v;
    __syncthreads();
  }
  float Fv = v;
  float g = IP[idx] - Fv;
  float mv = g;
  buf[s] = mv; __syncthreads();
  for (int off = 1; off < 256; off <<= 1){
    float tv = (s >= off) ? buf[s - off] : -3.0e38f;
    __syncthreads();
    mv = fmaxf(mv, tv); buf[s] = mv;
    __syncthreads();
  }
  Fo[idx] = Fv; Go[idx] = g; Mo[idx] = mv;
}

// Fused MFMA mLSTM attention (unchanged).
__global__ __launch_bounds__(256) void attn_kernel(
    const u16* __restrict__ Q, const u16* __restrict__ Kb, const u16* __restrict__ V,
    const float* __restrict__ G, const float* __restrict__ Mx, const float* __restrict__ F,
    const u16* __restrict__ Ab, const u16* __restrict__ UPb,
    const float* __restrict__ ng, const float* __restrict__ nb,
    const float* __restrict__ skip, u16* __restrict__ Yb)
{
  int bh = blockIdx.y, b = bh >> 2, h = bh & 3;
  int tt = blockIdx.x, t0 = tt * 64;
  int tid = threadIdx.x;
  int w = tid >> 6, lane = tid & 63, lm = lane & 15, q = lane >> 4;
  int gbase = bh * 256;

  __shared__ alignas(16) u16 Qs[64*136];
  __shared__ alignas(16) u16 Ks[64*136];
  __shared__ alignas(16) u16 Vt[128*72];
  __shared__ alignas(16) u16 Ps[64*72];
  __shared__ float rs[64];

#pragma unroll
  for (int c = tid; c < 1024; c += 256){
    int r = c >> 4, ch = c & 15;
    *(uint4*)&Qs[r*136 + ch*8] =
      *(const uint4*)&Q[((size_t)(b*256 + t0 + r))*512 + h*128 + ch*8];
  }
  if (tid < 64) rs[tid] = 0.f;

  float mrow[4];
#pragma unroll
  for (int r = 0; r < 4; r++) mrow[r] = Mx[gbase + t0 + w*16 + q*4 + r];

  float4v acc2[8] = {};
  const float scale = 0.08838834764831845f;

  for (int ss = 0; ss <= tt; ss++){
    int s0 = ss * 64;
    __syncthreads();
#pragma unroll
    for (int c = tid; c < 1024; c += 256){
      int r = c >> 4, ch = c & 15;
      *(uint4*)&Ks[r*136 + ch*8] =
        *(const uint4*)&Kb[((size_t)(b*256 + s0 + r))*512 + h*128 + ch*8];
    }
#pragma unroll
    for (int c = tid; c < 1024; c += 256){
      int sl = c & 63, db = c >> 6;
      ushort8v v = *(const ushort8v*)&V[((size_t)(b*256 + s0 + sl))*512 + h*128 + db*8];
#pragma unroll
      for (int j = 0; j < 8; j++) Vt[(db*8 + j)*72 + sl] = v[j];
    }
    __syncthreads();
    float4v sacc[4] = {};
#pragma unroll
    for (int k0 = 0; k0 < 128; k0 += 32){
      short8 a = *(const short8*)&Qs[(w*16 + lm)*136 + k0 + q*8];
#pragma unroll
      for (int j = 0; j < 4; j++){
        short8 bb = *(const short8*)&Ks[(j*16 + lm)*136 + k0 + q*8];
        sacc[j] = __builtin_amdgcn_mfma_f32_16x16x32_bf16(a, bb, sacc[j], 0, 0, 0);
      }
    }
    float rp[4] = {0.f, 0.f, 0.f, 0.f};
#pragma unroll
    for (int j = 0; j < 4; j++){
      int scol = s0 + j*16 + lm;
      float gq = G[gbase + scol];
#pragma unroll
      for (int r = 0; r < 4; r++){
        int trow = t0 + w*16 + q*4 + r;
        float cval = (scol <= trow) ? sacc[j][r]*scale*__expf(gq - mrow[r]) : 0.f;
        Ps[(w*16 + q*4 + r)*72 + j*16 + lm] = f2b(cval);
        rp[r] += cval;
      }
    }
#pragma unroll
    for (int r = 0; r < 4; r++){
#pragma unroll
      for (int m = 1; m < 16; m <<= 1) rp[r] += __shfl_xor(rp[r], m, 16);
      if (lm == 0) rs[w*16 + q*4 + r] += rp[r];
    }
#pragma unroll
    for (int k0 = 0; k0 < 64; k0 += 32){
      short8 a = *(const short8*)&Ps[(w*16 + lm)*72 + k0 + q*8];
#pragma unroll
      for (int jd = 0; jd < 8; jd++){
        short8 bb = *(const short8*)&Vt[(jd*16 + lm)*72 + k0 + q*8];
        acc2[jd] = __builtin_amdgcn_mfma_f32_16x16x32_bf16(a, bb, acc2[jd], 0, 0, 0);
      }
    }
  }
  __syncthreads();
#pragma unroll
  for (int r = 0; r < 4; r++){
    int rl = w*16 + q*4 + r;
    int t = t0 + rl;
    float Fv = F[gbase + t];
    float nrm = fmaxf(fabsf(rs[rl]), __expf(-(Fv + mrow[r])));
    float inv = 1.f / nrm;
    float vv[8];
    float su = 0.f;
#pragma unroll
    for (int jd = 0; jd < 8; jd++){ vv[jd] = acc2[jd][r]*inv; su += vv[jd]; }
#pragma unroll
    for (int m = 1; m < 16; m <<= 1) su += __shfl_xor(su, m, 16);
    float mu = su * (1.f/128.f);
    float sq = 0.f;
#pragma unroll
    for (int jd = 0; jd < 8; jd++){ vv[jd] -= mu; sq += vv[jd]*vv[jd]; }
#pragma unroll
    for (int m = 1; m < 16; m <<= 1) sq += __shfl_xor(sq, m, 16);
    float rstd = rsqrtf(sq * (1.f/128.f) + 1e-6f);
#pragma unroll
    for (int jd = 0; jd < 8; jd++){
      int c = h*128 + jd*16 + lm;
      float hv = vv[jd]*rstd*ng[c] + nb[c];
      float av = b2f(Ab[(size_t)t*512 + c]);
      float zg = b2f(UPb[(size_t)t*1024 + 512 + c]);
      float sz = zg / (1.f + __expf(-zg));
      Yb[(size_t)t*512 + c] = f2b((hv + skip[c]*av)*sz);
    }
  }
}

// sLSTM recurrence: ONE WAVE per (b,h). R in 256 VGPRs (4 x 64 fp32 per lane,
// lane = output dim e). No barriers, no LDS. h broadcast via v_readlane.
// 8 independent accumulator chains; gate/X loads prefetched one step ahead.
__global__ __launch_bounds__(64) void scan_kernel(
    const float* __restrict__ IT, const float* __restrict__ FT,
    const float* __restrict__ ZT, const float* __restrict__ OT,
    const float* __restrict__ Ri, const float* __restrict__ Rf,
    const float* __restrict__ Rz, const float* __restrict__ Ro,
    const float* __restrict__ sng, const float* __restrict__ snb,
    float* __restrict__ Xr){
  int bh = blockIdx.x; int b = bh >> 2, h = bh & 3;
  int e = threadIdx.x;
  float r0[64], r1[64], r2[64], r3[64];
  const float* Rp0 = Ri + h*4096; const float* Rp1 = Rf + h*4096;
  const float* Rp2 = Rz + h*4096; const float* Rp3 = Ro + h*4096;
#pragma unroll
  for (int d = 0; d < 64; d++){
    r0[d] = Rp0[d*64 + e];
    r1[d] = Rp1[d*64 + e];
    r2[d] = Rp2[d*64 + e];
    r3[d] = Rp3[d*64 + e];
  }
  float gw = sng[h*64 + e], bw = snb[h*64 + e];
  float hS = 0.f, cS = 0.f, nS = 0.f, mS = 0.f;
  size_t rowbase = ((size_t)b*256)*256 + h*64 + e;
  float i0 = IT[rowbase], f0 = FT[rowbase], z0 = ZT[rowbase], o0 = OT[rowbase];
  float xc = Xr[rowbase];
  for (int s = 0; s < 256; s++){
    float iN = 0.f, fN = 0.f, zN = 0.f, oN = 0.f, xN = 0.f;
    if (s < 255){
      size_t nrow = rowbase + (size_t)(s + 1)*256;
      iN = IT[nrow]; fN = FT[nrow]; zN = ZT[nrow]; oN = OT[nrow]; xN = Xr[nrow];
    }
    // matvec: 2 chains per gate
    float ai0 = 0.f, ai1 = 0.f, af0 = 0.f, af1 = 0.f;
    float az0 = 0.f, az1 = 0.f, ao0 = 0.f, ao1 = 0.f;
#pragma unroll
    for (int d = 0; d < 64; d += 2){
      float h0 = __builtin_bit_cast(float,
          __builtin_amdgcn_readlane(__builtin_bit_cast(int, hS), d));
      float h1 = __builtin_bit_cast(float,
          __builtin_amdgcn_readlane(__builtin_bit_cast(int, hS), d + 1));
      ai0 += h0*r0[d]; ai1 += h1*r0[d+1];
      af0 += h0*r1[d]; af1 += h1*r1[d+1];
      az0 += h0*r2[d]; az1 += h1*r2[d+1];
      ao0 += h0*r3[d]; ao1 += h1*r3[d+1];
    }
    float ip = i0 + ai0 + ai1;
    float fp = f0 + af0 + af1;
    float zp = tanhf(z0 + az0 + az1);
    float op = 1.f / (1.f + __expf(-(o0 + ao0 + ao1)));
    float mn = fmaxf(fp + mS, ip);
    float ig = __expf(ip - mn);
    float fg = __expf(fp + mS - mn);
    cS = fg*cS + ig*zp;
    nS = fg*nS + ig;
    mS = mn;
    hS = op * cS / nS;
    // headnorm over the wave's 64 lanes
    float su = hS, sq = hS*hS;
#pragma unroll
    for (int o = 32; o > 0; o >>= 1){
      su += __shfl_xor(su, o, 64);
      sq += __shfl_xor(sq, o, 64);
    }
    float mu = su * (1.f/64.f);
    float var = fmaxf(sq * (1.f/64.f) - mu*mu, 0.f);
    float nv = (hS - mu) * rsqrtf(var + 1e-6f) * gw + bw;
    Xr[rowbase + (size_t)s*256] = xc + nv;
    xc = xN; i0 = iN; f0 = fN; z0 = zN; o0 = oN;
  }
}

// FFN activation: P = gelu_tanh(g) * u, ushort8 vectorized
__global__ __launch_bounds__(256) void ffn_act_kernel(const u16* __restrict__ GU,
                                                      u16* __restrict__ P){
  long long gid = (long long)blockIdx.x * 256 + threadIdx.x;   // T*44
  int j8 = (int)(gid % 44) * 8; long long t = gid / 44;
  ushort8v gv = *(const ushort8v*)&GU[(size_t)t*704 + j8];
  ushort8v uv = *(const ushort8v*)&GU[(size_t)t*704 + 352 + j8];
  ushort8v o8;
#pragma unroll
  for (int i = 0; i < 8; i++){
    float g = b2f(gv[i]);
    float u = b2f(uv[i]);
    float inner = 0.7978845608028654f * (g + 0.044715f*g*g*g);
    float gel = 0.5f * g * (1.f + tanhf(inner));
    o8[i] = f2b(gel * u);
  }
  *(ushort8v*)&P[(size_t)t*352 + j8] = o8;
}

// output head: relu(last@W1+b1)@W2+b2, write in detected dtype
__global__ __launch_bounds__(64) void head_kernel(const float* __restrict__ X,
    const float* __restrict__ W1, const float* __restrict__ b1,
    const float* __restrict__ W2, const float* __restrict__ b2,
    void* out, const int* __restrict__ flag){
  int b = blockIdx.x, j = threadIdx.x;
  __shared__ float L[256];
  __shared__ float H1[64];
  for (int i = j; i < 256; i += 64) L[i] = X[((size_t)(b*256 + 255))*256 + i];
  __syncthreads();
  float acc = b1[j];
  for (int d = 0; d < 256; d++) acc += L[d] * W1[d*64 + j];
  H1[j] = fmaxf(acc, 0.f);
  __syncthreads();
  if (j < 3){
    float o = b2[j];
    for (int k2 = 0; k2 < 64; k2++) o += H1[k2] * W2[k2*3 + j];
    if (*flag) ((u16*)out)[b*3 + j] = f2b(o);
    else       ((float*)out)[b*3 + j] = o;
  }
}

// ----------------------------- launch --------------------------------------
extern "C" void kernel_launch(void* const* d_in, const int* in_sizes, int n_in,
                              void* d_out, int out_size, void* d_ws, size_t ws_size,
                              hipStream_t stream)
{
  if (n_in != IN_N) return;
  for (int i = 0; i < IN_N; i++) if ((long long)in_sizes[i] != IN_SIZES[i]) return;
  if (ws_size < (size_t)WS_END * 4) return;
  if (out_size != 384) return;

  float* ws = (float*)d_ws;
  float* cv = ws;
  auto cvp = [&](int i){ return cv + CVOFF.off[i]; };

  int*   flag = (int*)(ws + OFF_FLAG);
  float* IP   = ws + OFF_IP;
  float* FP   = ws + OFF_FP;
  float* Fb   = ws + OFF_F;
  float* Gb   = ws + OFF_G;
  float* Mb   = ws + OFF_M;
  float* X    = ws + OFF_X;
  u16*   XNb  = (u16*)(ws + OFF_XN);
  u16*   UPb  = (u16*)(ws + OFF_UP);
  u16*   Ab   = (u16*)(ws + OFF_A);
  u16*   Qb   = (u16*)(ws + OFF_Q);
  u16*   Kbb  = (u16*)(ws + OFF_K);
  u16*   Vb   = (u16*)(ws + OFF_V);
  u16*   WTb  = (u16*)(ws + OFF_WT);
  // overlays (lifetimes disjoint):
  float* CAT = ws + OFF_V;
  u16*   Yb  = Qb;
  u16*   ACb = Ab;
  float* ITf = ws + OFF_K;
  float* FTf = ws + OFF_V;
  float* ZTf = ws + OFF_Q;
  float* OTf = ws + OFF_UP;
  u16*   GUb = UPb;
  u16*   Pb  = Ab;

  auto wt = [&](int widx){ return WTb + WTO[widx]; };

  InPtrs ptrs;
  for (int i = 0; i < IN_N; i++) ptrs.p[i] = d_in[i];

  const int M = 32768;
  detect_kernel<<<1, 64, 0, stream>>>(d_in[7], flag);
  int cvblocks = (int)((CV_TOTAL + 255) / 256);
  convert_kernel<<<cvblocks, 256, 0, stream>>>(ptrs, cv, flag);
  wtrans_kernel<<<dim3(32, 16, 11), 256, 0, stream>>>(ptrs, WTb, flag);
  cat_kernel<<<5120, 256, 0, stream>>>(cvp(0), (const int*)d_in[1], (const int*)d_in[2],
                                       cvp(3), cvp(4), CAT);
  gemm_kernel<float, float><<<dim3(4, 512), 256, 0, stream>>>(CAT, 40, cvp(5), cvp(6),
      X, 256, nullptr, M, 256, 40);
  // ---- mLSTM block ----
  ln_kernel<<<8192, 256, 0, stream>>>(X, cvp(7), cvp(8), XNb, 1e-5f);
  gemm_mfma<u16><<<dim3(8, 256), 256, 0, stream>>>(XNb, 256, wt(0), cvp(10),
      UPb, 1024, nullptr, 1024, 256);
  conv_silu_kernel<<<8192, 256, 0, stream>>>(UPb, 1024, 512, cvp(11), cvp(12), Ab);
  gemm_mfma<u16><<<dim3(4, 256), 256, 0, stream>>>(Ab, 512, wt(1), cvp(14),
      Qb, 512, nullptr, 512, 512);
  gemm_mfma<u16><<<dim3(4, 256), 256, 0, stream>>>(Ab, 512, wt(2), cvp(16),
      Kbb, 512, nullptr, 512, 512);
  gemm_mfma<u16><<<dim3(4, 256), 256, 0, stream>>>(UPb, 1024, wt(3), cvp(18),
      Vb, 512, nullptr, 512, 512);
  gates_kernel<<<M, 256, 0, stream>>>(Qb, Kbb, Vb, cvp(19), cvp(20), cvp(21), cvp(22), IP, FP);
  fscan_kernel<<<512, 256, 0, stream>>>(IP, FP, Fb, Gb, Mb);
  attn_kernel<<<dim3(4, 512), 256, 0, stream>>>(Qb, Kbb, Vb, Gb, Mb, Fb,
      Ab, UPb, cvp(24), cvp(25), cvp(23), Yb);
  gemm_mfma<float><<<dim3(2, 256), 256, 0, stream>>>(Yb, 512, wt(4), cvp(27),
      X, 256, X, 256, 512);
  // ---- sLSTM block ----
  ln_kernel<<<8192, 256, 0, stream>>>(X, cvp(28), cvp(29), XNb, 1e-5f);
  conv_silu_kernel<<<4096, 256, 0, stream>>>(XNb, 256, 256, cvp(30), cvp(31), ACb);
  gemm_mfma<float><<<dim3(2, 256), 256, 0, stream>>>(ACb, 256, wt(5), cvp(33),
      ITf, 256, nullptr, 256, 256);
  gemm_mfma<float><<<dim3(2, 256), 256, 0, stream>>>(ACb, 256, wt(6), cvp(35),
      FTf, 256, nullptr, 256, 256);
  gemm_mfma<float><<<dim3(2, 256), 256, 0, stream>>>(XNb, 256, wt(7), cvp(37),
      ZTf, 256, nullptr, 256, 256);
  gemm_mfma<float><<<dim3(2, 256), 256, 0, stream>>>(XNb, 256, wt(8), cvp(39),
      OTf, 256, nullptr, 256, 256);
  scan_kernel<<<512, 64, 0, stream>>>(ITf, FTf, ZTf, OTf, cvp(40), cvp(41), cvp(42), cvp(43),
      cvp(44), cvp(45), X);
  // ---- FFN ----
  ln_kernel<<<8192, 256, 0, stream>>>(X, cvp(46), cvp(47), XNb, 1e-5f);
  gemm_mfma<u16><<<dim3(6, 256), 256, 0, stream>>>(XNb, 256, wt(9), cvp(49),
      GUb, 704, nullptr, 704, 256);
  ffn_act_kernel<<<5632, 256, 0, stream>>>(GUb, Pb);
  gemm_mfma<float><<<dim3(2, 256), 256, 0, stream>>>(Pb, 352, wt(10), cvp(51),
      X, 256, X, 256, 352);
  // ---- head ----
  head_kernel<<<128, 64, 0, stream>>>(X, cvp(52), cvp(53), cvp(54), cvp(55), d_out, flag);
}